// Round 7
// baseline (208.161 us; speedup 1.0000x reference)
//
#include <hip/hip_runtime.h>
#include <hip/hip_bf16.h>

typedef __attribute__((ext_vector_type(8))) short bf16x8;
typedef __attribute__((ext_vector_type(4))) float f32x4;

// Q prescale folds log2(e) so attn can use raw exp2 (v_exp_f32):
// 0.0625 * 1.4426950408889634 = 0.09016844
#define QSCALE 0.09016844f

__device__ __forceinline__ unsigned short f2b(float f) {
    union { float f; unsigned int u; } v; v.f = f;
    unsigned int u = v.u;
    unsigned int r = (u + 0x7FFFu + ((u >> 16) & 1u)) >> 16;  // RNE
    return (unsigned short)r;
}
__device__ __forceinline__ float b2f(unsigned short h) {
    union { unsigned int u; float f; } v; v.u = ((unsigned int)h) << 16;
    return v.f;
}
__device__ __forceinline__ unsigned pk2(float a, float b) {
    union { __hip_bfloat162 h; unsigned u; } c;
    c.h = __float22bfloat162_rn(make_float2(a, b));
    return c.u;
}

// ---------- prep (bf16 path): weights + lin_w + biases + activations ----------
__global__ __launch_bounds__(256) void prep_main(
    const float* __restrict__ WQ, const float* __restrict__ WK,
    const float* __restrict__ WV, const float* __restrict__ LW,
    const float* __restrict__ Qb, const float* __restrict__ Kb,
    const float* __restrict__ Vb,
    const float* __restrict__ x, const float* __restrict__ peQ,
    const float* __restrict__ peK,
    unsigned short* __restrict__ WQt, unsigned short* __restrict__ WKt,
    unsigned short* __restrict__ WVt, unsigned short* __restrict__ LWt,
    unsigned short* __restrict__ Bq, unsigned short* __restrict__ Bk,
    unsigned short* __restrict__ Bv,
    unsigned short* __restrict__ xb, unsigned short* __restrict__ peQb,
    unsigned short* __restrict__ peKb) {
    int b = blockIdx.x, t = threadIdx.x;
    if (b < 288) {
        const float* W; unsigned short* Wt; int h, d0, D; float sc = 1.0f;
        if (b < 128)      { W = WQ; Wt = WQt; h = b >> 4;   d0 = (b & 15) * 64; D = 1024; sc = QSCALE; }
        else if (b < 256) { int bb = b - 128; W = WK; Wt = WKt; h = bb >> 4; d0 = (bb & 15) * 64; D = 1024; }
        else              { int bb = b - 256; W = WV; Wt = WVt; h = bb >> 2; d0 = (bb & 3) * 64;  D = 256; }
        __shared__ float Ts[32][65];
        int dr = t >> 2, k0 = (t & 3) * 8;
        const float* src = W + (h * D + d0 + dr) * 32 + k0;
        float4 u0 = *(const float4*)src;
        float4 u1 = *(const float4*)(src + 4);
        Ts[k0 + 0][dr] = u0.x; Ts[k0 + 1][dr] = u0.y; Ts[k0 + 2][dr] = u0.z; Ts[k0 + 3][dr] = u0.w;
        Ts[k0 + 4][dr] = u1.x; Ts[k0 + 5][dr] = u1.y; Ts[k0 + 6][dr] = u1.z; Ts[k0 + 7][dr] = u1.w;
        __syncthreads();
        int k = t >> 3, dc = (t & 7) * 8;
        union { unsigned short s[8]; uint4 v; } pk;
#pragma unroll
        for (int i = 0; i < 8; i++) pk.s[i] = f2b(Ts[k][dc + i] * sc);
        *(uint4*)(Wt + (h * 32 + k) * D + d0 + dc) = pk.v;
    } else if (b < 320) {
        int base = (b - 288) * 2048 + t * 8;
        const float* sp = LW + base;
        float4 u0 = *(const float4*)sp;
        float4 u1 = *(const float4*)(sp + 4);
        union { unsigned u[4]; uint4 v; } pk;
        pk.u[0] = pk2(u0.x, u0.y); pk.u[1] = pk2(u0.z, u0.w);
        pk.u[2] = pk2(u1.x, u1.y); pk.u[3] = pk2(u1.z, u1.w);
        *(uint4*)(LWt + base) = pk.v;
    } else if (b == 320) {
        Bq[t] = f2b(Qb[t] * QSCALE); Bk[t] = f2b(Kb[t]); Bv[t] = f2b(Vb[t]);
    } else {
        int idx = (b - 321) * 2048 + t * 8;
        const float* sp; unsigned short* dp;
        if (idx < 1048576)      { sp = x + idx;                dp = xb + idx; }
        else if (idx < 4194304) { sp = peQ + (idx - 1048576);  dp = peQb + (idx - 1048576); }
        else                    { sp = peK + (idx - 4194304);  dp = peKb + (idx - 4194304); }
        float4 u0 = *(const float4*)sp;
        float4 u1 = *(const float4*)(sp + 4);
        union { unsigned u[4]; uint4 v; } pk;
        pk.u[0] = pk2(u0.x, u0.y); pk.u[1] = pk2(u0.z, u0.w);
        pk.u[2] = pk2(u1.x, u1.y); pk.u[3] = pk2(u1.z, u1.w);
        *(uint4*)dp = pk.v;
    }
}

// ---------- prep (fallback): weights + biases only ----------
__global__ __launch_bounds__(256) void prep_fb(
    const float* __restrict__ WQ, const float* __restrict__ WK,
    const float* __restrict__ WV,
    const float* __restrict__ Qb, const float* __restrict__ Kb,
    const float* __restrict__ Vb,
    unsigned short* __restrict__ WQt, unsigned short* __restrict__ WKt,
    unsigned short* __restrict__ WVt,
    unsigned short* __restrict__ Bq, unsigned short* __restrict__ Bk,
    unsigned short* __restrict__ Bv) {
    int b = blockIdx.x, t = threadIdx.x;
    if (b < 288) {
        const float* W; unsigned short* Wt; int h, d0, D; float sc = 1.0f;
        if (b < 128)      { W = WQ; Wt = WQt; h = b >> 4;   d0 = (b & 15) * 64; D = 1024; sc = QSCALE; }
        else if (b < 256) { int bb = b - 128; W = WK; Wt = WKt; h = bb >> 4; d0 = (bb & 15) * 64; D = 1024; }
        else              { int bb = b - 256; W = WV; Wt = WVt; h = bb >> 2; d0 = (bb & 3) * 64;  D = 256; }
        __shared__ float Ts[32][65];
        int dr = t >> 2, k0 = (t & 3) * 8;
        const float* src = W + (h * D + d0 + dr) * 32 + k0;
        float4 u0 = *(const float4*)src;
        float4 u1 = *(const float4*)(src + 4);
        Ts[k0 + 0][dr] = u0.x; Ts[k0 + 1][dr] = u0.y; Ts[k0 + 2][dr] = u0.z; Ts[k0 + 3][dr] = u0.w;
        Ts[k0 + 4][dr] = u1.x; Ts[k0 + 5][dr] = u1.y; Ts[k0 + 6][dr] = u1.z; Ts[k0 + 7][dr] = u1.w;
        __syncthreads();
        int k = t >> 3, dc = (t & 7) * 8;
        union { unsigned short s[8]; uint4 v; } pk;
#pragma unroll
        for (int i = 0; i < 8; i++) pk.s[i] = f2b(Ts[k][dc + i] * sc);
        *(uint4*)(Wt + (h * 32 + k) * D + d0 + dc) = pk.v;
    } else {
        Bq[t] = f2b(Qb[t] * QSCALE); Bk[t] = f2b(Kb[t]); Bv[t] = f2b(Vb[t]);
    }
}

// ---------- fused Q/K/V projections (768 blocks, 64x64 tiles, BK=64) ----------
template <bool ABF16>
__global__ __launch_bounds__(256) void proj_fused(
    const void* __restrict__ xv,
    const void* __restrict__ peQv, const void* __restrict__ peKv,
    const unsigned short* __restrict__ WQt, const unsigned short* __restrict__ WKt,
    const unsigned short* __restrict__ WVt,
    const unsigned short* __restrict__ Bq, const unsigned short* __restrict__ Bk,
    const unsigned short* __restrict__ Bv,
    unsigned short* __restrict__ Qc, unsigned short* __restrict__ KV) {
    __shared__ unsigned short As[64 * 72];
    __shared__ unsigned short Bs[64 * 72];
    int bx = blockIdx.x;
    int which = bx >> 8, bb = bx & 255;
    const void* A1; const unsigned short* Bt; const unsigned short* bias; int K;
    if (which == 0)      { A1 = peQv; Bt = WQt; bias = Bq; K = 1024; }
    else if (which == 1) { A1 = peKv; Bt = WKt; bias = Bk; K = 1024; }
    else                 { A1 = peQv; Bt = WVt; bias = Bv; K = 256; }
    int mb = bb & 63, nb = bb >> 6;
    int m0 = mb * 64, n0 = nb * 64;
    int t = threadIdx.x, w = t >> 6, lane = t & 63;
    int ln = lane & 15, q8 = (lane >> 4) * 8;
    int wm = (w >> 1) * 32, wn = (w & 1) * 32;
    int sr = t >> 3, sc = (t & 7) * 8;
    f32x4 acc[2][2];
#pragma unroll
    for (int i = 0; i < 2; i++)
#pragma unroll
        for (int j = 0; j < 2; j++) acc[i][j] = (f32x4){0.f, 0.f, 0.f, 0.f};
    for (int kb = 0; kb < K; kb += 64) {
#pragma unroll
        for (int half = 0; half < 2; half++) {
            int r = sr + half * 32;
            int c = kb + sc;
            if (ABF16) {
                const unsigned short* ap = (c < 256)
                    ? ((const unsigned short*)xv + (m0 + r) * 256 + c)
                    : ((const unsigned short*)A1 + (m0 + r) * 768 + (c - 256));
                *(uint4*)&As[r * 72 + sc] = *(const uint4*)ap;
            } else {
                const float* ap = (c < 256)
                    ? ((const float*)xv + (m0 + r) * 256 + c)
                    : ((const float*)A1 + (m0 + r) * 768 + (c - 256));
                float4 u0 = *(const float4*)ap;
                float4 u1 = *(const float4*)(ap + 4);
                union { unsigned u[4]; uint4 v; } pk;
                pk.u[0] = pk2(u0.x, u0.y); pk.u[1] = pk2(u0.z, u0.w);
                pk.u[2] = pk2(u1.x, u1.y); pk.u[3] = pk2(u1.z, u1.w);
                *(uint4*)&As[r * 72 + sc] = pk.v;
            }
            *(uint4*)&Bs[r * 72 + sc] = *(const uint4*)(Bt + (n0 + r) * K + c);
        }
        __syncthreads();
#pragma unroll
        for (int ks = 0; ks < 64; ks += 32) {
            bf16x8 a[2], b[2];
#pragma unroll
            for (int i = 0; i < 2; i++) {
                a[i] = *(const bf16x8*)&As[(wm + i * 16 + ln) * 72 + ks + q8];
                b[i] = *(const bf16x8*)&Bs[(wn + i * 16 + ln) * 72 + ks + q8];
            }
#pragma unroll
            for (int i = 0; i < 2; i++)
#pragma unroll
                for (int j = 0; j < 2; j++)
                    acc[i][j] = __builtin_amdgcn_mfma_f32_16x16x32_bf16(a[i], b[j], acc[i][j], 0, 0, 0);
        }
        __syncthreads();
    }
#pragma unroll
    for (int j = 0; j < 2; j++) {
        int ncol = n0 + wn + j * 16 + ln;
        float bv = b2f(bias[ncol]);
        int h2 = ncol >> 5, din = ncol & 31;
#pragma unroll
        for (int i = 0; i < 2; i++) {
            int rbase = m0 + wm + i * 16 + ((lane >> 4) * 4);
            if (which == 0) {
#pragma unroll
                for (int r = 0; r < 4; r++)
                    Qc[(rbase + r) * 256 + ncol] = f2b(acc[i][j][r] + bv);
            } else if (which == 1) {
#pragma unroll
                for (int r = 0; r < 4; r++) {
                    int key = rbase + r;
                    int T2 = key >> 6, k6 = key & 63;
                    int kt = ((k6 >> 2) & 1) + ((k6 >> 4) & 2);
                    int ln2 = ((k6 >> 3) & 3) * 4 + (k6 & 3);
                    int addr = (h2 * 64 + T2) * 4096 + kt * 512
                             + ((din >> 3) * 16 + ln2) * 8 + (din & 7);
                    KV[addr] = f2b(acc[i][j][r] + bv);
                }
            } else {
                int key = rbase;
                int T2 = key >> 6, k6 = key & 63;
                int chunk = 4 + ((din >> 4) << 1) + ((k6 >> 5) & 1);
                int lane2 = ((k6 >> 3) & 3) * 16 + (din & 15);
                int addr = (h2 * 64 + T2) * 4096 + chunk * 512 + lane2 * 8 + (k6 & 7);
                uint2 vv;
                vv.x = pk2(acc[i][j][0] + bv, acc[i][j][1] + bv);
                vv.y = pk2(acc[i][j][2] + bv, acc[i][j][3] + bv);
                *(uint2*)(KV + addr) = vv;
            }
        }
    }
}

// ---------- flash attention v4-REP2: MEASUREMENT BUILD (resubmit) ----------
// The v4 body executed twice in-kernel (rep loop, re-initialized accumulators,
// identical Xc written both reps -- benign). Purpose: attn has been invariant
// at ~37-40 us across 4 structures while pipe arithmetic says ~10-17 us; the
// five 40-us harness fills hide it from top-5. Doubling surfaces it WITH
// counters. Round-6 run died to an infra flake (same signature as round 2,
// which passed on identical resubmit). dur/2 = true attn cost.
__global__ __launch_bounds__(512, 2) void attn_kernel(
    const unsigned short* __restrict__ Qc,
    const unsigned short* __restrict__ KV,
    unsigned short* __restrict__ Xc) {
    __shared__ float Om[8][32][65];
    __shared__ float Ls[8][64];
    int head = blockIdx.x & 7;
    int qb = blockIdx.x >> 3;
    int t = threadIdx.x, w = t >> 6, lane = t & 63;
    int ln = lane & 15, quad = lane >> 4, q8 = quad * 8;
    int q0 = qb * 64;
    bf16x8 qfv[4];
#pragma unroll
    for (int qf = 0; qf < 4; qf++)
        qfv[qf] = *(const bf16x8*)(Qc + (q0 + qf * 16 + ln) * 256 + head * 32 + q8);
    const unsigned short* kv = KV + (head * 64 + w * 8) * 4096 + lane * 8;
    const f32x4 z = {0.f, 0.f, 0.f, 0.f};
#pragma unroll 1
    for (int rep = 0; rep < 2; ++rep) {
        f32x4 o[4][2];
        float lts[4] = {0.f, 0.f, 0.f, 0.f};
#pragma unroll
        for (int qf = 0; qf < 4; qf++)
#pragma unroll
            for (int hh = 0; hh < 2; hh++) o[qf][hh] = (f32x4){0.f, 0.f, 0.f, 0.f};
        bf16x8 k0 = *(const bf16x8*)(kv + 0);
        bf16x8 k1 = *(const bf16x8*)(kv + 512);
        bf16x8 k2 = *(const bf16x8*)(kv + 1024);
        bf16x8 k3 = *(const bf16x8*)(kv + 1536);
        bf16x8 v0 = *(const bf16x8*)(kv + 2048);
        bf16x8 v1 = *(const bf16x8*)(kv + 2560);
        bf16x8 v2 = *(const bf16x8*)(kv + 3072);
        bf16x8 v3 = *(const bf16x8*)(kv + 3584);
#pragma unroll 1
        for (int it = 0; it < 8; it++) {
            int nit = (it < 7) ? (it + 1) : 7;
            const unsigned short* nkv = kv + nit * 4096;
            bf16x8 nk0 = *(const bf16x8*)(nkv + 0);
            bf16x8 nk1 = *(const bf16x8*)(nkv + 512);
            bf16x8 nk2 = *(const bf16x8*)(nkv + 1024);
            bf16x8 nk3 = *(const bf16x8*)(nkv + 1536);
            bf16x8 nv0 = *(const bf16x8*)(nkv + 2048);
            bf16x8 nv1 = *(const bf16x8*)(nkv + 2560);
            bf16x8 nv2 = *(const bf16x8*)(nkv + 3072);
            bf16x8 nv3 = *(const bf16x8*)(nkv + 3584);
#pragma unroll
            for (int qf = 0; qf < 4; qf++) {
                f32x4 s0 = __builtin_amdgcn_mfma_f32_16x16x32_bf16(k0, qfv[qf], z, 0, 0, 0);
                f32x4 s1 = __builtin_amdgcn_mfma_f32_16x16x32_bf16(k1, qfv[qf], z, 0, 0, 0);
                f32x4 s2 = __builtin_amdgcn_mfma_f32_16x16x32_bf16(k2, qfv[qf], z, 0, 0, 0);
                f32x4 s3 = __builtin_amdgcn_mfma_f32_16x16x32_bf16(k3, qfv[qf], z, 0, 0, 0);
                float p0[4], p1[4], p2[4], p3[4];
#pragma unroll
                for (int r = 0; r < 4; r++) {
                    p0[r] = __builtin_amdgcn_exp2f(s0[r]);
                    p1[r] = __builtin_amdgcn_exp2f(s1[r]);
                    p2[r] = __builtin_amdgcn_exp2f(s2[r]);
                    p3[r] = __builtin_amdgcn_exp2f(s3[r]);
                }
                float psum = 0.f;
#pragma unroll
                for (int r = 0; r < 4; r++) psum += (p0[r] + p1[r]) + (p2[r] + p3[r]);
                lts[qf] += psum;
                union { unsigned u[4]; bf16x8 v; } b0, b1;
                b0.u[0] = pk2(p0[0], p0[1]); b0.u[1] = pk2(p0[2], p0[3]);
                b0.u[2] = pk2(p1[0], p1[1]); b0.u[3] = pk2(p1[2], p1[3]);
                b1.u[0] = pk2(p2[0], p2[1]); b1.u[1] = pk2(p2[2], p2[3]);
                b1.u[2] = pk2(p3[0], p3[1]); b1.u[3] = pk2(p3[2], p3[3]);
                o[qf][0] = __builtin_amdgcn_mfma_f32_16x16x32_bf16(v0, b0.v, o[qf][0], 0, 0, 0);
                o[qf][0] = __builtin_amdgcn_mfma_f32_16x16x32_bf16(v1, b1.v, o[qf][0], 0, 0, 0);
                o[qf][1] = __builtin_amdgcn_mfma_f32_16x16x32_bf16(v2, b0.v, o[qf][1], 0, 0, 0);
                o[qf][1] = __builtin_amdgcn_mfma_f32_16x16x32_bf16(v3, b1.v, o[qf][1], 0, 0, 0);
            }
            k0 = nk0; k1 = nk1; k2 = nk2; k3 = nk3;
            v0 = nv0; v1 = nv1; v2 = nv2; v3 = nv3;
        }
#pragma unroll
        for (int qf = 0; qf < 4; qf++) {
            float l = lts[qf];
            l += __shfl_xor(l, 16, 64);
            l += __shfl_xor(l, 32, 64);
#pragma unroll
            for (int r = 0; r < 4; r++) {
                Om[w][quad * 4 + r][qf * 16 + ln] = o[qf][0][r];
                Om[w][16 + quad * 4 + r][qf * 16 + ln] = o[qf][1][r];
            }
            if (quad == 0) Ls[w][qf * 16 + ln] = l;
        }
        __syncthreads();
        int q6 = t & 63, d = (t >> 6) * 4;
        float num[4] = {0.f, 0.f, 0.f, 0.f};
        float den = 0.f;
#pragma unroll
        for (int w2 = 0; w2 < 8; w2++) {
            den += Ls[w2][q6];
#pragma unroll
            for (int i = 0; i < 4; i++) num[i] += Om[w2][d + i][q6];
        }
        float inv = 1.f / den;
        uint2 outv;
        outv.x = pk2(num[0] * inv, num[1] * inv);
        outv.y = pk2(num[2] * inv, num[3] * inv);
        *(uint2*)(Xc + (q0 + q6) * 256 + head * 32 + d) = outv;
        __syncthreads();
    }
}

// ---------- final GEMM: d_out f32 = Xc(bf16) @ lin_w^T + lin_b ----------
template <bool BBF16>
__global__ __launch_bounds__(256) void gemm_out(
    const unsigned short* __restrict__ A,
    const void* __restrict__ LWv,
    const float* __restrict__ Lb,
    float* __restrict__ C) {
    __shared__ unsigned short As[64 * 72];
    __shared__ unsigned short Bs[64 * 72];
    int mb = blockIdx.x & 63, nb = blockIdx.x >> 6;
    int m0 = mb * 64, n0 = nb * 64;
    int t = threadIdx.x, w = t >> 6, lane = t & 63;
    int ln = lane & 15, q8 = (lane >> 4) * 8;
    int wm = (w >> 1) * 32, wn = (w & 1) * 32;
    int sr = t >> 3, sc = (t & 7) * 8;
    f32x4 acc[2][2];
#pragma unroll
    for (int i = 0; i < 2; i++)
#pragma unroll
        for (int j = 0; j < 2; j++) acc[i][j] = (f32x4){0.f, 0.f, 0.f, 0.f};
    for (int kb = 0; kb < 256; kb += 64) {
#pragma unroll
        for (int half = 0; half < 2; half++) {
            int r = sr + half * 32;
            int c = kb + sc;
            *(uint4*)&As[r * 72 + sc] = *(const uint4*)(A + (m0 + r) * 256 + c);
            if (BBF16) {
                *(uint4*)&Bs[r * 72 + sc] =
                    *(const uint4*)((const unsigned short*)LWv + (n0 + r) * 256 + c);
            } else {
                const float* bp = (const float*)LWv + (n0 + r) * 256 + c;
                float4 u0 = *(const float4*)bp;
                float4 u1 = *(const float4*)(bp + 4);
                union { unsigned u[4]; uint4 v; } pk;
                pk.u[0] = pk2(u0.x, u0.y); pk.u[1] = pk2(u0.z, u0.w);
                pk.u[2] = pk2(u1.x, u1.y); pk.u[3] = pk2(u1.z, u1.w);
                *(uint4*)&Bs[r * 72 + sc] = pk.v;
            }
        }
        __syncthreads();
#pragma unroll
        for (int ks = 0; ks < 64; ks += 32) {
            bf16x8 a[2], b[2];
#pragma unroll
            for (int i = 0; i < 2; i++) {
                a[i] = *(const bf16x8*)&As[(wm + i * 16 + ln) * 72 + ks + q8];
                b[i] = *(const bf16x8*)&Bs[(wn + i * 16 + ln) * 72 + ks + q8];
            }
#pragma unroll
            for (int i = 0; i < 2; i++)
#pragma unroll
                for (int j = 0; j < 2; j++)
                    acc[i][j] = __builtin_amdgcn_mfma_f32_16x16x32_bf16(a[i], b[j], acc[i][j], 0, 0, 0);
        }
        __syncthreads();
    }
#pragma unroll
    for (int j = 0; j < 2; j++) {
        int ncol = n0 + wn + j * 16 + ln;
        float bv = Lb[ncol];
#pragma unroll
        for (int i = 0; i < 2; i++) {
            int rbase = m0 + wm + i * 16 + ((lane >> 4) * 4);
#pragma unroll
            for (int r = 0; r < 4; r++)
                C[(rbase + r) * 256 + ncol] = acc[i][j][r] + bv;
        }
    }
}

extern "C" void kernel_launch(void* const* d_in, const int* in_sizes, int n_in,
                              void* d_out, int out_size, void* d_ws, size_t ws_size,
                              hipStream_t stream) {
    const float* input_x = (const float*)d_in[0];
    const float* pe_Q    = (const float*)d_in[1];
    const float* pe_K    = (const float*)d_in[2];
    // d_in[3] = A (unused)
    const float* WQ = (const float*)d_in[4];
    const float* WK = (const float*)d_in[5];
    const float* WV = (const float*)d_in[6];
    const float* Qb = (const float*)d_in[7];
    const float* Kb = (const float*)d_in[8];
    const float* Vb = (const float*)d_in[9];
    const float* lw = (const float*)d_in[10];
    const float* lb = (const float*)d_in[11];
    float* outp = (float*)d_out;

    unsigned short* ws = (unsigned short*)d_ws;
    unsigned short* WQt = ws;                  // 262144
    unsigned short* WKt = WQt + 262144;        // 262144
    unsigned short* WVt = WKt + 262144;        // 65536
    unsigned short* LWt = WVt + 65536;         // 65536
    unsigned short* Bq  = LWt + 65536;         // 256 x3
    unsigned short* Bk  = Bq + 256;
    unsigned short* Bv  = Bk + 256;
    unsigned short* xb   = Bv + 256;           // 1048576
    unsigned short* peQb = xb + 1048576;       // 3145728
    unsigned short* peKb = peQb + 3145728;     // 3145728
    unsigned short* Qc   = peKb + 3145728;     // 1048576
    unsigned short* KVb  = Qc + 1048576;       // 2097152
    unsigned short* Xc   = KVb + 2097152;      // 1048576
    size_t need = (size_t)(Xc + 1048576 - ws) * 2;

    if (ws_size >= need) {
        prep_main<<<dim3(3905), dim3(256), 0, stream>>>(
            WQ, WK, WV, lw, Qb, Kb, Vb, input_x, pe_Q, pe_K,
            WQt, WKt, WVt, LWt, Bq, Bk, Bv, xb, peQb, peKb);
        proj_fused<true><<<dim3(768), dim3(256), 0, stream>>>(
            xb, peQb, peKb, WQt, WKt, WVt, Bq, Bk, Bv, Qc, KVb);
        attn_kernel<<<dim3(512), dim3(512), 0, stream>>>(Qc, KVb, Xc);
        gemm_out<true><<<dim3(256), dim3(256), 0, stream>>>(Xc, LWt, lb, outp);
    } else {
        // fallback (f32 staging), smaller footprint
        unsigned short* Qc2  = Bv + 256;
        unsigned short* KV2  = Qc2 + 1048576;
        unsigned short* Xc2  = KV2 + 2097152;
        prep_fb<<<dim3(289), dim3(256), 0, stream>>>(WQ, WK, WV, Qb, Kb, Vb,
                                                     WQt, WKt, WVt, Bq, Bk, Bv);
        proj_fused<false><<<dim3(768), dim3(256), 0, stream>>>(
            input_x, pe_Q, pe_K, WQt, WKt, WVt, Bq, Bk, Bv, Qc2, KV2);
        attn_kernel<<<dim3(512), dim3(512), 0, stream>>>(Qc2, KV2, Xc2);
        gemm_out<false><<<dim3(256), dim3(256), 0, stream>>>(Xc2, lw, lb, outp);
    }
}

// Round 8
// 190.282 us; speedup vs baseline: 1.0940x; 1.0940x over previous
//
#include <hip/hip_runtime.h>
#include <hip/hip_bf16.h>

typedef __attribute__((ext_vector_type(8))) short bf16x8;
typedef __attribute__((ext_vector_type(4))) float f32x4;

// Q prescale folds log2(e) so attn can use raw exp2 (v_exp_f32):
// 0.0625 * 1.4426950408889634 = 0.09016844
#define QSCALE 0.09016844f

__device__ __forceinline__ unsigned short f2b(float f) {
    union { float f; unsigned int u; } v; v.f = f;
    unsigned int u = v.u;
    unsigned int r = (u + 0x7FFFu + ((u >> 16) & 1u)) >> 16;  // RNE
    return (unsigned short)r;
}
__device__ __forceinline__ float b2f(unsigned short h) {
    union { unsigned int u; float f; } v; v.u = ((unsigned int)h) << 16;
    return v.f;
}
__device__ __forceinline__ unsigned pk2(float a, float b) {
    union { __hip_bfloat162 h; unsigned u; } c;
    c.h = __float22bfloat162_rn(make_float2(a, b));
    return c.u;
}

// ---------- prep (bf16 path): weights + lin_w + biases + activations ----------
__global__ __launch_bounds__(256) void prep_main(
    const float* __restrict__ WQ, const float* __restrict__ WK,
    const float* __restrict__ WV, const float* __restrict__ LW,
    const float* __restrict__ Qb, const float* __restrict__ Kb,
    const float* __restrict__ Vb,
    const float* __restrict__ x, const float* __restrict__ peQ,
    const float* __restrict__ peK,
    unsigned short* __restrict__ WQt, unsigned short* __restrict__ WKt,
    unsigned short* __restrict__ WVt, unsigned short* __restrict__ LWt,
    unsigned short* __restrict__ Bq, unsigned short* __restrict__ Bk,
    unsigned short* __restrict__ Bv,
    unsigned short* __restrict__ xb, unsigned short* __restrict__ peQb,
    unsigned short* __restrict__ peKb) {
    int b = blockIdx.x, t = threadIdx.x;
    if (b < 288) {
        const float* W; unsigned short* Wt; int h, d0, D; float sc = 1.0f;
        if (b < 128)      { W = WQ; Wt = WQt; h = b >> 4;   d0 = (b & 15) * 64; D = 1024; sc = QSCALE; }
        else if (b < 256) { int bb = b - 128; W = WK; Wt = WKt; h = bb >> 4; d0 = (bb & 15) * 64; D = 1024; }
        else              { int bb = b - 256; W = WV; Wt = WVt; h = bb >> 2; d0 = (bb & 3) * 64;  D = 256; }
        __shared__ float Ts[32][65];
        int dr = t >> 2, k0 = (t & 3) * 8;
        const float* src = W + (h * D + d0 + dr) * 32 + k0;
        float4 u0 = *(const float4*)src;
        float4 u1 = *(const float4*)(src + 4);
        Ts[k0 + 0][dr] = u0.x; Ts[k0 + 1][dr] = u0.y; Ts[k0 + 2][dr] = u0.z; Ts[k0 + 3][dr] = u0.w;
        Ts[k0 + 4][dr] = u1.x; Ts[k0 + 5][dr] = u1.y; Ts[k0 + 6][dr] = u1.z; Ts[k0 + 7][dr] = u1.w;
        __syncthreads();
        int k = t >> 3, dc = (t & 7) * 8;
        union { unsigned short s[8]; uint4 v; } pk;
#pragma unroll
        for (int i = 0; i < 8; i++) pk.s[i] = f2b(Ts[k][dc + i] * sc);
        *(uint4*)(Wt + (h * 32 + k) * D + d0 + dc) = pk.v;
    } else if (b < 320) {
        int base = (b - 288) * 2048 + t * 8;
        const float* sp = LW + base;
        float4 u0 = *(const float4*)sp;
        float4 u1 = *(const float4*)(sp + 4);
        union { unsigned u[4]; uint4 v; } pk;
        pk.u[0] = pk2(u0.x, u0.y); pk.u[1] = pk2(u0.z, u0.w);
        pk.u[2] = pk2(u1.x, u1.y); pk.u[3] = pk2(u1.z, u1.w);
        *(uint4*)(LWt + base) = pk.v;
    } else if (b == 320) {
        Bq[t] = f2b(Qb[t] * QSCALE); Bk[t] = f2b(Kb[t]); Bv[t] = f2b(Vb[t]);
    } else {
        int idx = (b - 321) * 2048 + t * 8;
        const float* sp; unsigned short* dp;
        if (idx < 1048576)      { sp = x + idx;                dp = xb + idx; }
        else if (idx < 4194304) { sp = peQ + (idx - 1048576);  dp = peQb + (idx - 1048576); }
        else                    { sp = peK + (idx - 4194304);  dp = peKb + (idx - 4194304); }
        float4 u0 = *(const float4*)sp;
        float4 u1 = *(const float4*)(sp + 4);
        union { unsigned u[4]; uint4 v; } pk;
        pk.u[0] = pk2(u0.x, u0.y); pk.u[1] = pk2(u0.z, u0.w);
        pk.u[2] = pk2(u1.x, u1.y); pk.u[3] = pk2(u1.z, u1.w);
        *(uint4*)dp = pk.v;
    }
}

// ---------- prep (fallback): weights + biases only ----------
__global__ __launch_bounds__(256) void prep_fb(
    const float* __restrict__ WQ, const float* __restrict__ WK,
    const float* __restrict__ WV,
    const float* __restrict__ Qb, const float* __restrict__ Kb,
    const float* __restrict__ Vb,
    unsigned short* __restrict__ WQt, unsigned short* __restrict__ WKt,
    unsigned short* __restrict__ WVt,
    unsigned short* __restrict__ Bq, unsigned short* __restrict__ Bk,
    unsigned short* __restrict__ Bv) {
    int b = blockIdx.x, t = threadIdx.x;
    if (b < 288) {
        const float* W; unsigned short* Wt; int h, d0, D; float sc = 1.0f;
        if (b < 128)      { W = WQ; Wt = WQt; h = b >> 4;   d0 = (b & 15) * 64; D = 1024; sc = QSCALE; }
        else if (b < 256) { int bb = b - 128; W = WK; Wt = WKt; h = bb >> 4; d0 = (bb & 15) * 64; D = 1024; }
        else              { int bb = b - 256; W = WV; Wt = WVt; h = bb >> 2; d0 = (bb & 3) * 64;  D = 256; }
        __shared__ float Ts[32][65];
        int dr = t >> 2, k0 = (t & 3) * 8;
        const float* src = W + (h * D + d0 + dr) * 32 + k0;
        float4 u0 = *(const float4*)src;
        float4 u1 = *(const float4*)(src + 4);
        Ts[k0 + 0][dr] = u0.x; Ts[k0 + 1][dr] = u0.y; Ts[k0 + 2][dr] = u0.z; Ts[k0 + 3][dr] = u0.w;
        Ts[k0 + 4][dr] = u1.x; Ts[k0 + 5][dr] = u1.y; Ts[k0 + 6][dr] = u1.z; Ts[k0 + 7][dr] = u1.w;
        __syncthreads();
        int k = t >> 3, dc = (t & 7) * 8;
        union { unsigned short s[8]; uint4 v; } pk;
#pragma unroll
        for (int i = 0; i < 8; i++) pk.s[i] = f2b(Ts[k][dc + i] * sc);
        *(uint4*)(Wt + (h * 32 + k) * D + d0 + dc) = pk.v;
    } else {
        Bq[t] = f2b(Qb[t] * QSCALE); Bk[t] = f2b(Kb[t]); Bv[t] = f2b(Vb[t]);
    }
}

// ---------- fused Q/K/V projections (768 blocks, 64x64 tiles, BK=64) ----------
template <bool ABF16>
__global__ __launch_bounds__(256) void proj_fused(
    const void* __restrict__ xv,
    const void* __restrict__ peQv, const void* __restrict__ peKv,
    const unsigned short* __restrict__ WQt, const unsigned short* __restrict__ WKt,
    const unsigned short* __restrict__ WVt,
    const unsigned short* __restrict__ Bq, const unsigned short* __restrict__ Bk,
    const unsigned short* __restrict__ Bv,
    unsigned short* __restrict__ Qc, unsigned short* __restrict__ KV) {
    __shared__ unsigned short As[64 * 72];
    __shared__ unsigned short Bs[64 * 72];
    int bx = blockIdx.x;
    int which = bx >> 8, bb = bx & 255;
    const void* A1; const unsigned short* Bt; const unsigned short* bias; int K;
    if (which == 0)      { A1 = peQv; Bt = WQt; bias = Bq; K = 1024; }
    else if (which == 1) { A1 = peKv; Bt = WKt; bias = Bk; K = 1024; }
    else                 { A1 = peQv; Bt = WVt; bias = Bv; K = 256; }
    int mb = bb & 63, nb = bb >> 6;
    int m0 = mb * 64, n0 = nb * 64;
    int t = threadIdx.x, w = t >> 6, lane = t & 63;
    int ln = lane & 15, q8 = (lane >> 4) * 8;
    int wm = (w >> 1) * 32, wn = (w & 1) * 32;
    int sr = t >> 3, sc = (t & 7) * 8;
    f32x4 acc[2][2];
#pragma unroll
    for (int i = 0; i < 2; i++)
#pragma unroll
        for (int j = 0; j < 2; j++) acc[i][j] = (f32x4){0.f, 0.f, 0.f, 0.f};
    for (int kb = 0; kb < K; kb += 64) {
#pragma unroll
        for (int half = 0; half < 2; half++) {
            int r = sr + half * 32;
            int c = kb + sc;
            if (ABF16) {
                const unsigned short* ap = (c < 256)
                    ? ((const unsigned short*)xv + (m0 + r) * 256 + c)
                    : ((const unsigned short*)A1 + (m0 + r) * 768 + (c - 256));
                *(uint4*)&As[r * 72 + sc] = *(const uint4*)ap;
            } else {
                const float* ap = (c < 256)
                    ? ((const float*)xv + (m0 + r) * 256 + c)
                    : ((const float*)A1 + (m0 + r) * 768 + (c - 256));
                float4 u0 = *(const float4*)ap;
                float4 u1 = *(const float4*)(ap + 4);
                union { unsigned u[4]; uint4 v; } pk;
                pk.u[0] = pk2(u0.x, u0.y); pk.u[1] = pk2(u0.z, u0.w);
                pk.u[2] = pk2(u1.x, u1.y); pk.u[3] = pk2(u1.z, u1.w);
                *(uint4*)&As[r * 72 + sc] = pk.v;
            }
            *(uint4*)&Bs[r * 72 + sc] = *(const uint4*)(Bt + (n0 + r) * K + c);
        }
        __syncthreads();
#pragma unroll
        for (int ks = 0; ks < 64; ks += 32) {
            bf16x8 a[2], b[2];
#pragma unroll
            for (int i = 0; i < 2; i++) {
                a[i] = *(const bf16x8*)&As[(wm + i * 16 + ln) * 72 + ks + q8];
                b[i] = *(const bf16x8*)&Bs[(wn + i * 16 + ln) * 72 + ks + q8];
            }
#pragma unroll
            for (int i = 0; i < 2; i++)
#pragma unroll
                for (int j = 0; j < 2; j++)
                    acc[i][j] = __builtin_amdgcn_mfma_f32_16x16x32_bf16(a[i], b[j], acc[i][j], 0, 0, 0);
        }
        __syncthreads();
    }
#pragma unroll
    for (int j = 0; j < 2; j++) {
        int ncol = n0 + wn + j * 16 + ln;
        float bv = b2f(bias[ncol]);
        int h2 = ncol >> 5, din = ncol & 31;
#pragma unroll
        for (int i = 0; i < 2; i++) {
            int rbase = m0 + wm + i * 16 + ((lane >> 4) * 4);
            if (which == 0) {
#pragma unroll
                for (int r = 0; r < 4; r++)
                    Qc[(rbase + r) * 256 + ncol] = f2b(acc[i][j][r] + bv);
            } else if (which == 1) {
#pragma unroll
                for (int r = 0; r < 4; r++) {
                    int key = rbase + r;
                    int T2 = key >> 6, k6 = key & 63;
                    int kt = ((k6 >> 2) & 1) + ((k6 >> 4) & 2);
                    int ln2 = ((k6 >> 3) & 3) * 4 + (k6 & 3);
                    int addr = (h2 * 64 + T2) * 4096 + kt * 512
                             + ((din >> 3) * 16 + ln2) * 8 + (din & 7);
                    KV[addr] = f2b(acc[i][j][r] + bv);
                }
            } else {
                int key = rbase;
                int T2 = key >> 6, k6 = key & 63;
                int chunk = 4 + ((din >> 4) << 1) + ((k6 >> 5) & 1);
                int lane2 = ((k6 >> 3) & 3) * 16 + (din & 15);
                int addr = (h2 * 64 + T2) * 4096 + chunk * 512 + lane2 * 8 + (k6 & 7);
                uint2 vv;
                vv.x = pk2(acc[i][j][0] + bv, acc[i][j][1] + bv);
                vv.y = pk2(acc[i][j][2] + bv, acc[i][j][3] + bv);
                *(uint2*)(KV + addr) = vv;
            }
        }
    }
}

// ---------- flash attention v5: wave-owns-rows + LDS-shared KV + MFMA denominator ----------
// Round-7 counters: MfmaUtil 18.6% == exactly the MFMA work (13.8us of 73.7us
// rep2); VALUBusy 52% (~19us/pass); ~30% bubbles; VGPR=72 proves the compiler
// sank the K/V prefetch (needed ~120 regs) -> exposed load latency.
// v5 fixes both: (a) KV tile staged once per block into a 16KB LDS double
// buffer (structural pipeline, T14 issue-early/write-late; compiler can't sink
// it); (b) denominator via mfma(ones, P) -> kills 16 VALU adds/tile AND the
// whole Om/Ls cross-wave reduce epilogue (denominator becomes lane-local).
// Each wave owns 16 q-rows end-to-end; 4 waves/block; grid 512 = 2 blocks/CU;
// head = blockIdx&7 keeps one head per XCD L2.
__global__ __launch_bounds__(256, 2) void attn_kernel(
    const unsigned short* __restrict__ Qc,
    const unsigned short* __restrict__ KV,
    unsigned short* __restrict__ Xc) {
    __shared__ unsigned short Kt[2][4096];
    int head = blockIdx.x & 7;
    int qb = blockIdx.x >> 3;
    int tid = threadIdx.x, w = tid >> 6, lane = tid & 63;
    int ln = lane & 15, quad = lane >> 4, q8 = quad * 8;
    int q0 = qb * 64;
    int qrow = q0 + w * 16 + ln;
    bf16x8 qv = *(const bf16x8*)(Qc + qrow * 256 + head * 32 + q8);
    bf16x8 ones;
#pragma unroll
    for (int i = 0; i < 8; i++) ones[i] = (short)0x3F80;  // bf16 1.0
    const f32x4 z = {0.f, 0.f, 0.f, 0.f};
    f32x4 o0 = z, o1 = z, lacc = z;
    const unsigned short* panel = KV + head * 64 * 4096;
    // stage tile 0
    {
        const uint4* sp = (const uint4*)panel;
        *(uint4*)&Kt[0][tid * 16] = sp[tid * 2];
        *(uint4*)&Kt[0][tid * 16 + 8] = sp[tid * 2 + 1];
    }
    __syncthreads();
#pragma unroll 1
    for (int it = 0; it < 64; ++it) {
        int cur = it & 1;
        uint4 n0, n1;
        if (it < 63) {  // issue next-tile loads early (hide under compute)
            const uint4* ns = (const uint4*)(panel + (it + 1) * 4096);
            n0 = ns[tid * 2]; n1 = ns[tid * 2 + 1];
        }
        const unsigned short* kb = &Kt[cur][0];
        bf16x8 k0 = *(const bf16x8*)(kb + lane * 8);
        bf16x8 k1 = *(const bf16x8*)(kb + 512 + lane * 8);
        bf16x8 k2 = *(const bf16x8*)(kb + 1024 + lane * 8);
        bf16x8 k3 = *(const bf16x8*)(kb + 1536 + lane * 8);
        bf16x8 v0 = *(const bf16x8*)(kb + 2048 + lane * 8);
        bf16x8 v1 = *(const bf16x8*)(kb + 2560 + lane * 8);
        bf16x8 v2 = *(const bf16x8*)(kb + 3072 + lane * 8);
        bf16x8 v3 = *(const bf16x8*)(kb + 3584 + lane * 8);
        f32x4 s0 = __builtin_amdgcn_mfma_f32_16x16x32_bf16(k0, qv, z, 0, 0, 0);
        f32x4 s1 = __builtin_amdgcn_mfma_f32_16x16x32_bf16(k1, qv, z, 0, 0, 0);
        f32x4 s2 = __builtin_amdgcn_mfma_f32_16x16x32_bf16(k2, qv, z, 0, 0, 0);
        f32x4 s3 = __builtin_amdgcn_mfma_f32_16x16x32_bf16(k3, qv, z, 0, 0, 0);
        float p0[4], p1[4], p2[4], p3[4];
#pragma unroll
        for (int r = 0; r < 4; r++) {
            p0[r] = __builtin_amdgcn_exp2f(s0[r]);
            p1[r] = __builtin_amdgcn_exp2f(s1[r]);
            p2[r] = __builtin_amdgcn_exp2f(s2[r]);
            p3[r] = __builtin_amdgcn_exp2f(s3[r]);
        }
        union { unsigned u[4]; bf16x8 v; } b0, b1;
        b0.u[0] = pk2(p0[0], p0[1]); b0.u[1] = pk2(p0[2], p0[3]);
        b0.u[2] = pk2(p1[0], p1[1]); b0.u[3] = pk2(p1[2], p1[3]);
        b1.u[0] = pk2(p2[0], p2[1]); b1.u[1] = pk2(p2[2], p2[3]);
        b1.u[2] = pk2(p3[0], p3[1]); b1.u[3] = pk2(p3[2], p3[3]);
        // denominator on the MFMA pipe: every output row of mfma(ones,P) is
        // the key-sum for col q -> lane-local, no cross-wave reduce needed.
        lacc = __builtin_amdgcn_mfma_f32_16x16x32_bf16(ones, b0.v, lacc, 0, 0, 0);
        lacc = __builtin_amdgcn_mfma_f32_16x16x32_bf16(ones, b1.v, lacc, 0, 0, 0);
        o0 = __builtin_amdgcn_mfma_f32_16x16x32_bf16(v0, b0.v, o0, 0, 0, 0);
        o0 = __builtin_amdgcn_mfma_f32_16x16x32_bf16(v1, b1.v, o0, 0, 0, 0);
        o1 = __builtin_amdgcn_mfma_f32_16x16x32_bf16(v2, b0.v, o1, 0, 0, 0);
        o1 = __builtin_amdgcn_mfma_f32_16x16x32_bf16(v3, b1.v, o1, 0, 0, 0);
        __syncthreads();   // all waves done reading Kt[cur]
        if (it < 63) {
            int nxt = cur ^ 1;
            *(uint4*)&Kt[nxt][tid * 16] = n0;
            *(uint4*)&Kt[nxt][tid * 16 + 8] = n1;
        }
        __syncthreads();   // writes visible before next iter's reads
    }
    float inv = 1.f / lacc[0];
    uint2 r0v, r1v;
    r0v.x = pk2(o0[0] * inv, o0[1] * inv);
    r0v.y = pk2(o0[2] * inv, o0[3] * inv);
    r1v.x = pk2(o1[0] * inv, o1[1] * inv);
    r1v.y = pk2(o1[2] * inv, o1[3] * inv);
    unsigned short* xp = Xc + qrow * 256 + head * 32 + quad * 4;
    *(uint2*)(xp) = r0v;        // d = quad*4 + 0..3
    *(uint2*)(xp + 16) = r1v;   // d = 16 + quad*4 + 0..3
}

// ---------- final GEMM: d_out f32 = Xc(bf16) @ lin_w^T + lin_b ----------
template <bool BBF16>
__global__ __launch_bounds__(256) void gemm_out(
    const unsigned short* __restrict__ A,
    const void* __restrict__ LWv,
    const float* __restrict__ Lb,
    float* __restrict__ C) {
    __shared__ unsigned short As[64 * 72];
    __shared__ unsigned short Bs[64 * 72];
    int mb = blockIdx.x & 63, nb = blockIdx.x >> 6;
    int m0 = mb * 64, n0 = nb * 64;
    int t = threadIdx.x, w = t >> 6, lane = t & 63;
    int ln = lane & 15, q8 = (lane >> 4) * 8;
    int wm = (w >> 1) * 32, wn = (w & 1) * 32;
    int sr = t >> 3, sc = (t & 7) * 8;
    f32x4 acc[2][2];
#pragma unroll
    for (int i = 0; i < 2; i++)
#pragma unroll
        for (int j = 0; j < 2; j++) acc[i][j] = (f32x4){0.f, 0.f, 0.f, 0.f};
    for (int kb = 0; kb < 256; kb += 64) {
#pragma unroll
        for (int half = 0; half < 2; half++) {
            int r = sr + half * 32;
            int c = kb + sc;
            *(uint4*)&As[r * 72 + sc] = *(const uint4*)(A + (m0 + r) * 256 + c);
            if (BBF16) {
                *(uint4*)&Bs[r * 72 + sc] =
                    *(const uint4*)((const unsigned short*)LWv + (n0 + r) * 256 + c);
            } else {
                const float* bp = (const float*)LWv + (n0 + r) * 256 + c;
                float4 u0 = *(const float4*)bp;
                float4 u1 = *(const float4*)(bp + 4);
                union { unsigned u[4]; uint4 v; } pk;
                pk.u[0] = pk2(u0.x, u0.y); pk.u[1] = pk2(u0.z, u0.w);
                pk.u[2] = pk2(u1.x, u1.y); pk.u[3] = pk2(u1.z, u1.w);
                *(uint4*)&Bs[r * 72 + sc] = pk.v;
            }
        }
        __syncthreads();
#pragma unroll
        for (int ks = 0; ks < 64; ks += 32) {
            bf16x8 a[2], b[2];
#pragma unroll
            for (int i = 0; i < 2; i++) {
                a[i] = *(const bf16x8*)&As[(wm + i * 16 + ln) * 72 + ks + q8];
                b[i] = *(const bf16x8*)&Bs[(wn + i * 16 + ln) * 72 + ks + q8];
            }
#pragma unroll
            for (int i = 0; i < 2; i++)
#pragma unroll
                for (int j = 0; j < 2; j++)
                    acc[i][j] = __builtin_amdgcn_mfma_f32_16x16x32_bf16(a[i], b[j], acc[i][j], 0, 0, 0);
        }
        __syncthreads();
    }
#pragma unroll
    for (int j = 0; j < 2; j++) {
        int ncol = n0 + wn + j * 16 + ln;
        float bv = Lb[ncol];
#pragma unroll
        for (int i = 0; i < 2; i++) {
            int rbase = m0 + wm + i * 16 + ((lane >> 4) * 4);
#pragma unroll
            for (int r = 0; r < 4; r++)
                C[(rbase + r) * 256 + ncol] = acc[i][j][r] + bv;
        }
    }
}

extern "C" void kernel_launch(void* const* d_in, const int* in_sizes, int n_in,
                              void* d_out, int out_size, void* d_ws, size_t ws_size,
                              hipStream_t stream) {
    const float* input_x = (const float*)d_in[0];
    const float* pe_Q    = (const float*)d_in[1];
    const float* pe_K    = (const float*)d_in[2];
    // d_in[3] = A (unused)
    const float* WQ = (const float*)d_in[4];
    const float* WK = (const float*)d_in[5];
    const float* WV = (const float*)d_in[6];
    const float* Qb = (const float*)d_in[7];
    const float* Kb = (const float*)d_in[8];
    const float* Vb = (const float*)d_in[9];
    const float* lw = (const float*)d_in[10];
    const float* lb = (const float*)d_in[11];
    float* outp = (float*)d_out;

    unsigned short* ws = (unsigned short*)d_ws;
    unsigned short* WQt = ws;                  // 262144
    unsigned short* WKt = WQt + 262144;        // 262144
    unsigned short* WVt = WKt + 262144;        // 65536
    unsigned short* LWt = WVt + 65536;         // 65536
    unsigned short* Bq  = LWt + 65536;         // 256 x3
    unsigned short* Bk  = Bq + 256;
    unsigned short* Bv  = Bk + 256;
    unsigned short* xb   = Bv + 256;           // 1048576
    unsigned short* peQb = xb + 1048576;       // 3145728
    unsigned short* peKb = peQb + 3145728;     // 3145728
    unsigned short* Qc   = peKb + 3145728;     // 1048576
    unsigned short* KVb  = Qc + 1048576;       // 2097152
    unsigned short* Xc   = KVb + 2097152;      // 1048576
    size_t need = (size_t)(Xc + 1048576 - ws) * 2;

    if (ws_size >= need) {
        prep_main<<<dim3(3905), dim3(256), 0, stream>>>(
            WQ, WK, WV, lw, Qb, Kb, Vb, input_x, pe_Q, pe_K,
            WQt, WKt, WVt, LWt, Bq, Bk, Bv, xb, peQb, peKb);
        proj_fused<true><<<dim3(768), dim3(256), 0, stream>>>(
            xb, peQb, peKb, WQt, WKt, WVt, Bq, Bk, Bv, Qc, KVb);
        attn_kernel<<<dim3(512), dim3(256), 0, stream>>>(Qc, KVb, Xc);
        gemm_out<true><<<dim3(256), dim3(256), 0, stream>>>(Xc, LWt, lb, outp);
    } else {
        // fallback (f32 staging), smaller footprint
        unsigned short* Qc2  = Bv + 256;
        unsigned short* KV2  = Qc2 + 1048576;
        unsigned short* Xc2  = KV2 + 2097152;
        prep_fb<<<dim3(289), dim3(256), 0, stream>>>(WQ, WK, WV, Qb, Kb, Vb,
                                                     WQt, WKt, WVt, Bq, Bk, Bv);
        proj_fused<false><<<dim3(768), dim3(256), 0, stream>>>(
            input_x, pe_Q, pe_K, WQt, WKt, WVt, Bq, Bk, Bv, Qc2, KV2);
        attn_kernel<<<dim3(512), dim3(256), 0, stream>>>(Qc2, KV2, Xc2);
        gemm_out<false><<<dim3(256), dim3(256), 0, stream>>>(Xc2, lw, lb, outp);
    }
}

// Round 9
// 177.141 us; speedup vs baseline: 1.1751x; 1.0742x over previous
//
#include <hip/hip_runtime.h>
#include <hip/hip_bf16.h>

typedef __attribute__((ext_vector_type(8))) short bf16x8;
typedef __attribute__((ext_vector_type(4))) float f32x4;

// Q prescale folds log2(e) so attn can use raw exp2 (v_exp_f32):
// 0.0625 * 1.4426950408889634 = 0.09016844
#define QSCALE 0.09016844f

__device__ __forceinline__ unsigned short f2b(float f) {
    union { float f; unsigned int u; } v; v.f = f;
    unsigned int u = v.u;
    unsigned int r = (u + 0x7FFFu + ((u >> 16) & 1u)) >> 16;  // RNE
    return (unsigned short)r;
}
__device__ __forceinline__ float b2f(unsigned short h) {
    union { unsigned int u; float f; } v; v.u = ((unsigned int)h) << 16;
    return v.f;
}
__device__ __forceinline__ unsigned pk2(float a, float b) {
    union { __hip_bfloat162 h; unsigned u; } c;
    c.h = __float22bfloat162_rn(make_float2(a, b));
    return c.u;
}

// ---------- prep (bf16 path): weights + lin_w + biases + activations ----------
__global__ __launch_bounds__(256) void prep_main(
    const float* __restrict__ WQ, const float* __restrict__ WK,
    const float* __restrict__ WV, const float* __restrict__ LW,
    const float* __restrict__ Qb, const float* __restrict__ Kb,
    const float* __restrict__ Vb,
    const float* __restrict__ x, const float* __restrict__ peQ,
    const float* __restrict__ peK,
    unsigned short* __restrict__ WQt, unsigned short* __restrict__ WKt,
    unsigned short* __restrict__ WVt, unsigned short* __restrict__ LWt,
    unsigned short* __restrict__ Bq, unsigned short* __restrict__ Bk,
    unsigned short* __restrict__ Bv,
    unsigned short* __restrict__ xb, unsigned short* __restrict__ peQb,
    unsigned short* __restrict__ peKb) {
    int b = blockIdx.x, t = threadIdx.x;
    if (b < 288) {
        const float* W; unsigned short* Wt; int h, d0, D; float sc = 1.0f;
        if (b < 128)      { W = WQ; Wt = WQt; h = b >> 4;   d0 = (b & 15) * 64; D = 1024; sc = QSCALE; }
        else if (b < 256) { int bb = b - 128; W = WK; Wt = WKt; h = bb >> 4; d0 = (bb & 15) * 64; D = 1024; }
        else              { int bb = b - 256; W = WV; Wt = WVt; h = bb >> 2; d0 = (bb & 3) * 64;  D = 256; }
        __shared__ float Ts[32][65];
        int dr = t >> 2, k0 = (t & 3) * 8;
        const float* src = W + (h * D + d0 + dr) * 32 + k0;
        float4 u0 = *(const float4*)src;
        float4 u1 = *(const float4*)(src + 4);
        Ts[k0 + 0][dr] = u0.x; Ts[k0 + 1][dr] = u0.y; Ts[k0 + 2][dr] = u0.z; Ts[k0 + 3][dr] = u0.w;
        Ts[k0 + 4][dr] = u1.x; Ts[k0 + 5][dr] = u1.y; Ts[k0 + 6][dr] = u1.z; Ts[k0 + 7][dr] = u1.w;
        __syncthreads();
        int k = t >> 3, dc = (t & 7) * 8;
        union { unsigned short s[8]; uint4 v; } pk;
#pragma unroll
        for (int i = 0; i < 8; i++) pk.s[i] = f2b(Ts[k][dc + i] * sc);
        *(uint4*)(Wt + (h * 32 + k) * D + d0 + dc) = pk.v;
    } else if (b < 320) {
        int base = (b - 288) * 2048 + t * 8;
        const float* sp = LW + base;
        float4 u0 = *(const float4*)sp;
        float4 u1 = *(const float4*)(sp + 4);
        union { unsigned u[4]; uint4 v; } pk;
        pk.u[0] = pk2(u0.x, u0.y); pk.u[1] = pk2(u0.z, u0.w);
        pk.u[2] = pk2(u1.x, u1.y); pk.u[3] = pk2(u1.z, u1.w);
        *(uint4*)(LWt + base) = pk.v;
    } else if (b == 320) {
        Bq[t] = f2b(Qb[t] * QSCALE); Bk[t] = f2b(Kb[t]); Bv[t] = f2b(Vb[t]);
    } else {
        int idx = (b - 321) * 2048 + t * 8;
        const float* sp; unsigned short* dp;
        if (idx < 1048576)      { sp = x + idx;                dp = xb + idx; }
        else if (idx < 4194304) { sp = peQ + (idx - 1048576);  dp = peQb + (idx - 1048576); }
        else                    { sp = peK + (idx - 4194304);  dp = peKb + (idx - 4194304); }
        float4 u0 = *(const float4*)sp;
        float4 u1 = *(const float4*)(sp + 4);
        union { unsigned u[4]; uint4 v; } pk;
        pk.u[0] = pk2(u0.x, u0.y); pk.u[1] = pk2(u0.z, u0.w);
        pk.u[2] = pk2(u1.x, u1.y); pk.u[3] = pk2(u1.z, u1.w);
        *(uint4*)dp = pk.v;
    }
}

// ---------- prep (fallback): weights + biases only ----------
__global__ __launch_bounds__(256) void prep_fb(
    const float* __restrict__ WQ, const float* __restrict__ WK,
    const float* __restrict__ WV,
    const float* __restrict__ Qb, const float* __restrict__ Kb,
    const float* __restrict__ Vb,
    unsigned short* __restrict__ WQt, unsigned short* __restrict__ WKt,
    unsigned short* __restrict__ WVt,
    unsigned short* __restrict__ Bq, unsigned short* __restrict__ Bk,
    unsigned short* __restrict__ Bv) {
    int b = blockIdx.x, t = threadIdx.x;
    if (b < 288) {
        const float* W; unsigned short* Wt; int h, d0, D; float sc = 1.0f;
        if (b < 128)      { W = WQ; Wt = WQt; h = b >> 4;   d0 = (b & 15) * 64; D = 1024; sc = QSCALE; }
        else if (b < 256) { int bb = b - 128; W = WK; Wt = WKt; h = bb >> 4; d0 = (bb & 15) * 64; D = 1024; }
        else              { int bb = b - 256; W = WV; Wt = WVt; h = bb >> 2; d0 = (bb & 3) * 64;  D = 256; }
        __shared__ float Ts[32][65];
        int dr = t >> 2, k0 = (t & 3) * 8;
        const float* src = W + (h * D + d0 + dr) * 32 + k0;
        float4 u0 = *(const float4*)src;
        float4 u1 = *(const float4*)(src + 4);
        Ts[k0 + 0][dr] = u0.x; Ts[k0 + 1][dr] = u0.y; Ts[k0 + 2][dr] = u0.z; Ts[k0 + 3][dr] = u0.w;
        Ts[k0 + 4][dr] = u1.x; Ts[k0 + 5][dr] = u1.y; Ts[k0 + 6][dr] = u1.z; Ts[k0 + 7][dr] = u1.w;
        __syncthreads();
        int k = t >> 3, dc = (t & 7) * 8;
        union { unsigned short s[8]; uint4 v; } pk;
#pragma unroll
        for (int i = 0; i < 8; i++) pk.s[i] = f2b(Ts[k][dc + i] * sc);
        *(uint4*)(Wt + (h * 32 + k) * D + d0 + dc) = pk.v;
    } else {
        Bq[t] = f2b(Qb[t] * QSCALE); Bk[t] = f2b(Kb[t]); Bv[t] = f2b(Vb[t]);
    }
}

// ---------- fused Q/K/V projections (768 blocks, 64x64 tiles, BK=64) ----------
template <bool ABF16>
__global__ __launch_bounds__(256) void proj_fused(
    const void* __restrict__ xv,
    const void* __restrict__ peQv, const void* __restrict__ peKv,
    const unsigned short* __restrict__ WQt, const unsigned short* __restrict__ WKt,
    const unsigned short* __restrict__ WVt,
    const unsigned short* __restrict__ Bq, const unsigned short* __restrict__ Bk,
    const unsigned short* __restrict__ Bv,
    unsigned short* __restrict__ Qc, unsigned short* __restrict__ KV) {
    __shared__ unsigned short As[64 * 72];
    __shared__ unsigned short Bs[64 * 72];
    int bx = blockIdx.x;
    int which = bx >> 8, bb = bx & 255;
    const void* A1; const unsigned short* Bt; const unsigned short* bias; int K;
    if (which == 0)      { A1 = peQv; Bt = WQt; bias = Bq; K = 1024; }
    else if (which == 1) { A1 = peKv; Bt = WKt; bias = Bk; K = 1024; }
    else                 { A1 = peQv; Bt = WVt; bias = Bv; K = 256; }
    int mb = bb & 63, nb = bb >> 6;
    int m0 = mb * 64, n0 = nb * 64;
    int t = threadIdx.x, w = t >> 6, lane = t & 63;
    int ln = lane & 15, q8 = (lane >> 4) * 8;
    int wm = (w >> 1) * 32, wn = (w & 1) * 32;
    int sr = t >> 3, sc = (t & 7) * 8;
    f32x4 acc[2][2];
#pragma unroll
    for (int i = 0; i < 2; i++)
#pragma unroll
        for (int j = 0; j < 2; j++) acc[i][j] = (f32x4){0.f, 0.f, 0.f, 0.f};
    for (int kb = 0; kb < K; kb += 64) {
#pragma unroll
        for (int half = 0; half < 2; half++) {
            int r = sr + half * 32;
            int c = kb + sc;
            if (ABF16) {
                const unsigned short* ap = (c < 256)
                    ? ((const unsigned short*)xv + (m0 + r) * 256 + c)
                    : ((const unsigned short*)A1 + (m0 + r) * 768 + (c - 256));
                *(uint4*)&As[r * 72 + sc] = *(const uint4*)ap;
            } else {
                const float* ap = (c < 256)
                    ? ((const float*)xv + (m0 + r) * 256 + c)
                    : ((const float*)A1 + (m0 + r) * 768 + (c - 256));
                float4 u0 = *(const float4*)ap;
                float4 u1 = *(const float4*)(ap + 4);
                union { unsigned u[4]; uint4 v; } pk;
                pk.u[0] = pk2(u0.x, u0.y); pk.u[1] = pk2(u0.z, u0.w);
                pk.u[2] = pk2(u1.x, u1.y); pk.u[3] = pk2(u1.z, u1.w);
                *(uint4*)&As[r * 72 + sc] = pk.v;
            }
            *(uint4*)&Bs[r * 72 + sc] = *(const uint4*)(Bt + (n0 + r) * K + c);
        }
        __syncthreads();
#pragma unroll
        for (int ks = 0; ks < 64; ks += 32) {
            bf16x8 a[2], b[2];
#pragma unroll
            for (int i = 0; i < 2; i++) {
                a[i] = *(const bf16x8*)&As[(wm + i * 16 + ln) * 72 + ks + q8];
                b[i] = *(const bf16x8*)&Bs[(wn + i * 16 + ln) * 72 + ks + q8];
            }
#pragma unroll
            for (int i = 0; i < 2; i++)
#pragma unroll
                for (int j = 0; j < 2; j++)
                    acc[i][j] = __builtin_amdgcn_mfma_f32_16x16x32_bf16(a[i], b[j], acc[i][j], 0, 0, 0);
        }
        __syncthreads();
    }
#pragma unroll
    for (int j = 0; j < 2; j++) {
        int ncol = n0 + wn + j * 16 + ln;
        float bv = b2f(bias[ncol]);
        int h2 = ncol >> 5, din = ncol & 31;
#pragma unroll
        for (int i = 0; i < 2; i++) {
            int rbase = m0 + wm + i * 16 + ((lane >> 4) * 4);
            if (which == 0) {
#pragma unroll
                for (int r = 0; r < 4; r++)
                    Qc[(rbase + r) * 256 + ncol] = f2b(acc[i][j][r] + bv);
            } else if (which == 1) {
#pragma unroll
                for (int r = 0; r < 4; r++) {
                    int key = rbase + r;
                    int T2 = key >> 6, k6 = key & 63;
                    int kt = ((k6 >> 2) & 1) + ((k6 >> 4) & 2);
                    int ln2 = ((k6 >> 3) & 3) * 4 + (k6 & 3);
                    int addr = (h2 * 64 + T2) * 4096 + kt * 512
                             + ((din >> 3) * 16 + ln2) * 8 + (din & 7);
                    KV[addr] = f2b(acc[i][j][r] + bv);
                }
            } else {
                int key = rbase;
                int T2 = key >> 6, k6 = key & 63;
                int chunk = 4 + ((din >> 4) << 1) + ((k6 >> 5) & 1);
                int lane2 = ((k6 >> 3) & 3) * 16 + (din & 15);
                int addr = (h2 * 64 + T2) * 4096 + chunk * 512 + lane2 * 8 + (k6 & 7);
                uint2 vv;
                vv.x = pk2(acc[i][j][0] + bv, acc[i][j][1] + bv);
                vv.y = pk2(acc[i][j][2] + bv, acc[i][j][3] + bv);
                *(uint2*)(KV + addr) = vv;
            }
        }
    }
}

// ---------- flash attention v6: v4 + pinned prefetch + MFMA denominator ----------
// Round-7/8 diagnosis: v4 (reg KV) = 36.8us with 30% bubbles because hipcc
// sank the prefetch (VGPR=72 vs ~120 needed); v5 (LDS KV) = 48.9us (barrier
// serialization) but PROVED the VALU cuts work (VALUBusy 52->32%).
// v6 = v4 layout with:
//  - unroll-2 + two named tile reg sets (ta*/tb*): no reg-rotation movs;
//  - sched_barrier(0) after each load clump: loads can't sink past it, so
//    their ~600cyc latency hides under the other tile's 16-MFMA+exp2 block;
//  - denominator via mfma(ones,P) into lacc[qf]: kills psum adds + epilogue
//    shfl chain (v5-proven); Ls written straight from lacc[qf][0].
// Success indicator: VGPR_Count ~140-170 (pin worked). 8 waves/block,
// grid 512, head=blockIdx&7 (one head per XCD L2).
#define TILE_COMPUTE(K0_, K1_, K2_, K3_, V0_, V1_, V2_, V3_)                          \
    do {                                                                              \
        _Pragma("unroll")                                                             \
        for (int qf = 0; qf < 4; qf++) {                                              \
            f32x4 s0 = __builtin_amdgcn_mfma_f32_16x16x32_bf16(K0_, qfv[qf], z, 0, 0, 0); \
            f32x4 s1 = __builtin_amdgcn_mfma_f32_16x16x32_bf16(K1_, qfv[qf], z, 0, 0, 0); \
            f32x4 s2 = __builtin_amdgcn_mfma_f32_16x16x32_bf16(K2_, qfv[qf], z, 0, 0, 0); \
            f32x4 s3 = __builtin_amdgcn_mfma_f32_16x16x32_bf16(K3_, qfv[qf], z, 0, 0, 0); \
            float p0[4], p1[4], p2[4], p3[4];                                         \
            _Pragma("unroll")                                                         \
            for (int r = 0; r < 4; r++) {                                             \
                p0[r] = __builtin_amdgcn_exp2f(s0[r]);                                \
                p1[r] = __builtin_amdgcn_exp2f(s1[r]);                                \
                p2[r] = __builtin_amdgcn_exp2f(s2[r]);                                \
                p3[r] = __builtin_amdgcn_exp2f(s3[r]);                                \
            }                                                                         \
            union { unsigned u[4]; bf16x8 v; } pa, pb;                                \
            pa.u[0] = pk2(p0[0], p0[1]); pa.u[1] = pk2(p0[2], p0[3]);                 \
            pa.u[2] = pk2(p1[0], p1[1]); pa.u[3] = pk2(p1[2], p1[3]);                 \
            pb.u[0] = pk2(p2[0], p2[1]); pb.u[1] = pk2(p2[2], p2[3]);                 \
            pb.u[2] = pk2(p3[0], p3[1]); pb.u[3] = pk2(p3[2], p3[3]);                 \
            lacc[qf] = __builtin_amdgcn_mfma_f32_16x16x32_bf16(ones, pa.v, lacc[qf], 0, 0, 0); \
            lacc[qf] = __builtin_amdgcn_mfma_f32_16x16x32_bf16(ones, pb.v, lacc[qf], 0, 0, 0); \
            o[qf][0] = __builtin_amdgcn_mfma_f32_16x16x32_bf16(V0_, pa.v, o[qf][0], 0, 0, 0); \
            o[qf][0] = __builtin_amdgcn_mfma_f32_16x16x32_bf16(V1_, pb.v, o[qf][0], 0, 0, 0); \
            o[qf][1] = __builtin_amdgcn_mfma_f32_16x16x32_bf16(V2_, pa.v, o[qf][1], 0, 0, 0); \
            o[qf][1] = __builtin_amdgcn_mfma_f32_16x16x32_bf16(V3_, pb.v, o[qf][1], 0, 0, 0); \
        }                                                                             \
    } while (0)

__global__ __launch_bounds__(512, 2) void attn_kernel(
    const unsigned short* __restrict__ Qc,
    const unsigned short* __restrict__ KV,
    unsigned short* __restrict__ Xc) {
    __shared__ float Om[8][32][65];
    __shared__ float Ls[8][64];
    int head = blockIdx.x & 7;
    int qb = blockIdx.x >> 3;
    int t = threadIdx.x, w = t >> 6, lane = t & 63;
    int ln = lane & 15, quad = lane >> 4, q8 = quad * 8;
    int q0 = qb * 64;
    bf16x8 qfv[4];
#pragma unroll
    for (int qf = 0; qf < 4; qf++)
        qfv[qf] = *(const bf16x8*)(Qc + (q0 + qf * 16 + ln) * 256 + head * 32 + q8);
    const unsigned short* kv = KV + (head * 64 + w * 8) * 4096 + lane * 8;
    bf16x8 ones;
#pragma unroll
    for (int i = 0; i < 8; i++) ones[i] = (short)0x3F80;  // bf16 1.0
    const f32x4 z = {0.f, 0.f, 0.f, 0.f};
    f32x4 o[4][2];
    f32x4 lacc[4];
#pragma unroll
    for (int qf = 0; qf < 4; qf++) {
        o[qf][0] = z; o[qf][1] = z; lacc[qf] = z;
    }
    // prologue: tile set A <- tile 0
    bf16x8 ta0 = *(const bf16x8*)(kv + 0);
    bf16x8 ta1 = *(const bf16x8*)(kv + 512);
    bf16x8 ta2 = *(const bf16x8*)(kv + 1024);
    bf16x8 ta3 = *(const bf16x8*)(kv + 1536);
    bf16x8 ta4 = *(const bf16x8*)(kv + 2048);
    bf16x8 ta5 = *(const bf16x8*)(kv + 2560);
    bf16x8 ta6 = *(const bf16x8*)(kv + 3072);
    bf16x8 ta7 = *(const bf16x8*)(kv + 3584);
#pragma unroll 1
    for (int it = 0; it < 8; it += 2) {
        // load tile set B <- tile it+1, pinned before compute(A)
        const unsigned short* pB = kv + (it + 1) * 4096;
        bf16x8 tb0 = *(const bf16x8*)(pB + 0);
        bf16x8 tb1 = *(const bf16x8*)(pB + 512);
        bf16x8 tb2 = *(const bf16x8*)(pB + 1024);
        bf16x8 tb3 = *(const bf16x8*)(pB + 1536);
        bf16x8 tb4 = *(const bf16x8*)(pB + 2048);
        bf16x8 tb5 = *(const bf16x8*)(pB + 2560);
        bf16x8 tb6 = *(const bf16x8*)(pB + 3072);
        bf16x8 tb7 = *(const bf16x8*)(pB + 3584);
        __builtin_amdgcn_sched_barrier(0);
        TILE_COMPUTE(ta0, ta1, ta2, ta3, ta4, ta5, ta6, ta7);
        // load tile set A <- tile it+2 (guarded), pinned before compute(B)
        int nit2 = (it + 2 < 8) ? (it + 2) : 7;
        const unsigned short* pA = kv + nit2 * 4096;
        ta0 = *(const bf16x8*)(pA + 0);
        ta1 = *(const bf16x8*)(pA + 512);
        ta2 = *(const bf16x8*)(pA + 1024);
        ta3 = *(const bf16x8*)(pA + 1536);
        ta4 = *(const bf16x8*)(pA + 2048);
        ta5 = *(const bf16x8*)(pA + 2560);
        ta6 = *(const bf16x8*)(pA + 3072);
        ta7 = *(const bf16x8*)(pA + 3584);
        __builtin_amdgcn_sched_barrier(0);
        TILE_COMPUTE(tb0, tb1, tb2, tb3, tb4, tb5, tb6, tb7);
    }
#pragma unroll
    for (int qf = 0; qf < 4; qf++) {
#pragma unroll
        for (int r = 0; r < 4; r++) {
            Om[w][quad * 4 + r][qf * 16 + ln] = o[qf][0][r];
            Om[w][16 + quad * 4 + r][qf * 16 + ln] = o[qf][1][r];
        }
        if (quad == 0) Ls[w][qf * 16 + ln] = lacc[qf][0];
    }
    __syncthreads();
    int q6 = t & 63, d = (t >> 6) * 4;
    float num[4] = {0.f, 0.f, 0.f, 0.f};
    float den = 0.f;
#pragma unroll
    for (int w2 = 0; w2 < 8; w2++) {
        den += Ls[w2][q6];
#pragma unroll
        for (int i = 0; i < 4; i++) num[i] += Om[w2][d + i][q6];
    }
    float inv = 1.f / den;
    uint2 outv;
    outv.x = pk2(num[0] * inv, num[1] * inv);
    outv.y = pk2(num[2] * inv, num[3] * inv);
    *(uint2*)(Xc + (q0 + q6) * 256 + head * 32 + d) = outv;
}

// ---------- final GEMM: d_out f32 = Xc(bf16) @ lin_w^T + lin_b ----------
template <bool BBF16>
__global__ __launch_bounds__(256) void gemm_out(
    const unsigned short* __restrict__ A,
    const void* __restrict__ LWv,
    const float* __restrict__ Lb,
    float* __restrict__ C) {
    __shared__ unsigned short As[64 * 72];
    __shared__ unsigned short Bs[64 * 72];
    int mb = blockIdx.x & 63, nb = blockIdx.x >> 6;
    int m0 = mb * 64, n0 = nb * 64;
    int t = threadIdx.x, w = t >> 6, lane = t & 63;
    int ln = lane & 15, q8 = (lane >> 4) * 8;
    int wm = (w >> 1) * 32, wn = (w & 1) * 32;
    int sr = t >> 3, sc = (t & 7) * 8;
    f32x4 acc[2][2];
#pragma unroll
    for (int i = 0; i < 2; i++)
#pragma unroll
        for (int j = 0; j < 2; j++) acc[i][j] = (f32x4){0.f, 0.f, 0.f, 0.f};
    for (int kb = 0; kb < 256; kb += 64) {
#pragma unroll
        for (int half = 0; half < 2; half++) {
            int r = sr + half * 32;
            int c = kb + sc;
            *(uint4*)&As[r * 72 + sc] = *(const uint4*)(A + (m0 + r) * 256 + c);
            if (BBF16) {
                *(uint4*)&Bs[r * 72 + sc] =
                    *(const uint4*)((const unsigned short*)LWv + (n0 + r) * 256 + c);
            } else {
                const float* bp = (const float*)LWv + (n0 + r) * 256 + c;
                float4 u0 = *(const float4*)bp;
                float4 u1 = *(const float4*)(bp + 4);
                union { unsigned u[4]; uint4 v; } pk;
                pk.u[0] = pk2(u0.x, u0.y); pk.u[1] = pk2(u0.z, u0.w);
                pk.u[2] = pk2(u1.x, u1.y); pk.u[3] = pk2(u1.z, u1.w);
                *(uint4*)&Bs[r * 72 + sc] = pk.v;
            }
        }
        __syncthreads();
#pragma unroll
        for (int ks = 0; ks < 64; ks += 32) {
            bf16x8 a[2], b[2];
#pragma unroll
            for (int i = 0; i < 2; i++) {
                a[i] = *(const bf16x8*)&As[(wm + i * 16 + ln) * 72 + ks + q8];
                b[i] = *(const bf16x8*)&Bs[(wn + i * 16 + ln) * 72 + ks + q8];
            }
#pragma unroll
            for (int i = 0; i < 2; i++)
#pragma unroll
                for (int j = 0; j < 2; j++)
                    acc[i][j] = __builtin_amdgcn_mfma_f32_16x16x32_bf16(a[i], b[j], acc[i][j], 0, 0, 0);
        }
        __syncthreads();
    }
#pragma unroll
    for (int j = 0; j < 2; j++) {
        int ncol = n0 + wn + j * 16 + ln;
        float bv = Lb[ncol];
#pragma unroll
        for (int i = 0; i < 2; i++) {
            int rbase = m0 + wm + i * 16 + ((lane >> 4) * 4);
#pragma unroll
            for (int r = 0; r < 4; r++)
                C[(rbase + r) * 256 + ncol] = acc[i][j][r] + bv;
        }
    }
}

extern "C" void kernel_launch(void* const* d_in, const int* in_sizes, int n_in,
                              void* d_out, int out_size, void* d_ws, size_t ws_size,
                              hipStream_t stream) {
    const float* input_x = (const float*)d_in[0];
    const float* pe_Q    = (const float*)d_in[1];
    const float* pe_K    = (const float*)d_in[2];
    // d_in[3] = A (unused)
    const float* WQ = (const float*)d_in[4];
    const float* WK = (const float*)d_in[5];
    const float* WV = (const float*)d_in[6];
    const float* Qb = (const float*)d_in[7];
    const float* Kb = (const float*)d_in[8];
    const float* Vb = (const float*)d_in[9];
    const float* lw = (const float*)d_in[10];
    const float* lb = (const float*)d_in[11];
    float* outp = (float*)d_out;

    unsigned short* ws = (unsigned short*)d_ws;
    unsigned short* WQt = ws;                  // 262144
    unsigned short* WKt = WQt + 262144;        // 262144
    unsigned short* WVt = WKt + 262144;        // 65536
    unsigned short* LWt = WVt + 65536;         // 65536
    unsigned short* Bq  = LWt + 65536;         // 256 x3
    unsigned short* Bk  = Bq + 256;
    unsigned short* Bv  = Bk + 256;
    unsigned short* xb   = Bv + 256;           // 1048576
    unsigned short* peQb = xb + 1048576;       // 3145728
    unsigned short* peKb = peQb + 3145728;     // 3145728
    unsigned short* Qc   = peKb + 3145728;     // 1048576
    unsigned short* KVb  = Qc + 1048576;       // 2097152
    unsigned short* Xc   = KVb + 2097152;      // 1048576
    size_t need = (size_t)(Xc + 1048576 - ws) * 2;

    if (ws_size >= need) {
        prep_main<<<dim3(3905), dim3(256), 0, stream>>>(
            WQ, WK, WV, lw, Qb, Kb, Vb, input_x, pe_Q, pe_K,
            WQt, WKt, WVt, LWt, Bq, Bk, Bv, xb, peQb, peKb);
        proj_fused<true><<<dim3(768), dim3(256), 0, stream>>>(
            xb, peQb, peKb, WQt, WKt, WVt, Bq, Bk, Bv, Qc, KVb);
        attn_kernel<<<dim3(512), dim3(512), 0, stream>>>(Qc, KVb, Xc);
        gemm_out<true><<<dim3(256), dim3(256), 0, stream>>>(Xc, LWt, lb, outp);
    } else {
        // fallback (f32 staging), smaller footprint
        unsigned short* Qc2  = Bv + 256;
        unsigned short* KV2  = Qc2 + 1048576;
        unsigned short* Xc2  = KV2 + 2097152;
        prep_fb<<<dim3(289), dim3(256), 0, stream>>>(WQ, WK, WV, Qb, Kb, Vb,
                                                     WQt, WKt, WVt, Bq, Bk, Bv);
        proj_fused<false><<<dim3(768), dim3(256), 0, stream>>>(
            input_x, pe_Q, pe_K, WQt, WKt, WVt, Bq, Bk, Bv, Qc2, KV2);
        attn_kernel<<<dim3(512), dim3(512), 0, stream>>>(Qc2, KV2, Xc2);
        gemm_out<false><<<dim3(256), dim3(256), 0, stream>>>(Xc2, lw, lb, outp);
    }
}

// Round 10
// 174.749 us; speedup vs baseline: 1.1912x; 1.0137x over previous
//
#include <hip/hip_runtime.h>
#include <hip/hip_bf16.h>

typedef __attribute__((ext_vector_type(8))) short bf16x8;
typedef __attribute__((ext_vector_type(4))) float f32x4;

// Q prescale folds log2(e) so attn can use raw exp2 (v_exp_f32):
// 0.0625 * 1.4426950408889634 = 0.09016844
#define QSCALE 0.09016844f

__device__ __forceinline__ unsigned short f2b(float f) {
    union { float f; unsigned int u; } v; v.f = f;
    unsigned int u = v.u;
    unsigned int r = (u + 0x7FFFu + ((u >> 16) & 1u)) >> 16;  // RNE
    return (unsigned short)r;
}
__device__ __forceinline__ float b2f(unsigned short h) {
    union { unsigned int u; float f; } v; v.u = ((unsigned int)h) << 16;
    return v.f;
}
__device__ __forceinline__ unsigned pk2(float a, float b) {
    union { __hip_bfloat162 h; unsigned u; } c;
    c.h = __float22bfloat162_rn(make_float2(a, b));
    return c.u;
}

// ---------- prep (bf16 path): weights + lin_w + biases + activations ----------
__global__ __launch_bounds__(256) void prep_main(
    const float* __restrict__ WQ, const float* __restrict__ WK,
    const float* __restrict__ WV, const float* __restrict__ LW,
    const float* __restrict__ Qb, const float* __restrict__ Kb,
    const float* __restrict__ Vb,
    const float* __restrict__ x, const float* __restrict__ peQ,
    const float* __restrict__ peK,
    unsigned short* __restrict__ WQt, unsigned short* __restrict__ WKt,
    unsigned short* __restrict__ WVt, unsigned short* __restrict__ LWt,
    unsigned short* __restrict__ Bq, unsigned short* __restrict__ Bk,
    unsigned short* __restrict__ Bv,
    unsigned short* __restrict__ xb, unsigned short* __restrict__ peQb,
    unsigned short* __restrict__ peKb) {
    int b = blockIdx.x, t = threadIdx.x;
    if (b < 288) {
        const float* W; unsigned short* Wt; int h, d0, D; float sc = 1.0f;
        if (b < 128)      { W = WQ; Wt = WQt; h = b >> 4;   d0 = (b & 15) * 64; D = 1024; sc = QSCALE; }
        else if (b < 256) { int bb = b - 128; W = WK; Wt = WKt; h = bb >> 4; d0 = (bb & 15) * 64; D = 1024; }
        else              { int bb = b - 256; W = WV; Wt = WVt; h = bb >> 2; d0 = (bb & 3) * 64;  D = 256; }
        __shared__ float Ts[32][65];
        int dr = t >> 2, k0 = (t & 3) * 8;
        const float* src = W + (h * D + d0 + dr) * 32 + k0;
        float4 u0 = *(const float4*)src;
        float4 u1 = *(const float4*)(src + 4);
        Ts[k0 + 0][dr] = u0.x; Ts[k0 + 1][dr] = u0.y; Ts[k0 + 2][dr] = u0.z; Ts[k0 + 3][dr] = u0.w;
        Ts[k0 + 4][dr] = u1.x; Ts[k0 + 5][dr] = u1.y; Ts[k0 + 6][dr] = u1.z; Ts[k0 + 7][dr] = u1.w;
        __syncthreads();
        int k = t >> 3, dc = (t & 7) * 8;
        union { unsigned short s[8]; uint4 v; } pk;
#pragma unroll
        for (int i = 0; i < 8; i++) pk.s[i] = f2b(Ts[k][dc + i] * sc);
        *(uint4*)(Wt + (h * 32 + k) * D + d0 + dc) = pk.v;
    } else if (b < 320) {
        int base = (b - 288) * 2048 + t * 8;
        const float* sp = LW + base;
        float4 u0 = *(const float4*)sp;
        float4 u1 = *(const float4*)(sp + 4);
        union { unsigned u[4]; uint4 v; } pk;
        pk.u[0] = pk2(u0.x, u0.y); pk.u[1] = pk2(u0.z, u0.w);
        pk.u[2] = pk2(u1.x, u1.y); pk.u[3] = pk2(u1.z, u1.w);
        *(uint4*)(LWt + base) = pk.v;
    } else if (b == 320) {
        Bq[t] = f2b(Qb[t] * QSCALE); Bk[t] = f2b(Kb[t]); Bv[t] = f2b(Vb[t]);
    } else {
        int idx = (b - 321) * 2048 + t * 8;
        const float* sp; unsigned short* dp;
        if (idx < 1048576)      { sp = x + idx;                dp = xb + idx; }
        else if (idx < 4194304) { sp = peQ + (idx - 1048576);  dp = peQb + (idx - 1048576); }
        else                    { sp = peK + (idx - 4194304);  dp = peKb + (idx - 4194304); }
        float4 u0 = *(const float4*)sp;
        float4 u1 = *(const float4*)(sp + 4);
        union { unsigned u[4]; uint4 v; } pk;
        pk.u[0] = pk2(u0.x, u0.y); pk.u[1] = pk2(u0.z, u0.w);
        pk.u[2] = pk2(u1.x, u1.y); pk.u[3] = pk2(u1.z, u1.w);
        *(uint4*)dp = pk.v;
    }
}

// ---------- prep (fallback): weights + biases only ----------
__global__ __launch_bounds__(256) void prep_fb(
    const float* __restrict__ WQ, const float* __restrict__ WK,
    const float* __restrict__ WV,
    const float* __restrict__ Qb, const float* __restrict__ Kb,
    const float* __restrict__ Vb,
    unsigned short* __restrict__ WQt, unsigned short* __restrict__ WKt,
    unsigned short* __restrict__ WVt,
    unsigned short* __restrict__ Bq, unsigned short* __restrict__ Bk,
    unsigned short* __restrict__ Bv) {
    int b = blockIdx.x, t = threadIdx.x;
    if (b < 288) {
        const float* W; unsigned short* Wt; int h, d0, D; float sc = 1.0f;
        if (b < 128)      { W = WQ; Wt = WQt; h = b >> 4;   d0 = (b & 15) * 64; D = 1024; sc = QSCALE; }
        else if (b < 256) { int bb = b - 128; W = WK; Wt = WKt; h = bb >> 4; d0 = (bb & 15) * 64; D = 1024; }
        else              { int bb = b - 256; W = WV; Wt = WVt; h = bb >> 2; d0 = (bb & 3) * 64;  D = 256; }
        __shared__ float Ts[32][65];
        int dr = t >> 2, k0 = (t & 3) * 8;
        const float* src = W + (h * D + d0 + dr) * 32 + k0;
        float4 u0 = *(const float4*)src;
        float4 u1 = *(const float4*)(src + 4);
        Ts[k0 + 0][dr] = u0.x; Ts[k0 + 1][dr] = u0.y; Ts[k0 + 2][dr] = u0.z; Ts[k0 + 3][dr] = u0.w;
        Ts[k0 + 4][dr] = u1.x; Ts[k0 + 5][dr] = u1.y; Ts[k0 + 6][dr] = u1.z; Ts[k0 + 7][dr] = u1.w;
        __syncthreads();
        int k = t >> 3, dc = (t & 7) * 8;
        union { unsigned short s[8]; uint4 v; } pk;
#pragma unroll
        for (int i = 0; i < 8; i++) pk.s[i] = f2b(Ts[k][dc + i] * sc);
        *(uint4*)(Wt + (h * 32 + k) * D + d0 + dc) = pk.v;
    } else {
        Bq[t] = f2b(Qb[t] * QSCALE); Bk[t] = f2b(Kb[t]); Bv[t] = f2b(Vb[t]);
    }
}

// ---------- fused Q/K/V projections (768 blocks, 64x64 tiles, BK=64) ----------
template <bool ABF16>
__global__ __launch_bounds__(256) void proj_fused(
    const void* __restrict__ xv,
    const void* __restrict__ peQv, const void* __restrict__ peKv,
    const unsigned short* __restrict__ WQt, const unsigned short* __restrict__ WKt,
    const unsigned short* __restrict__ WVt,
    const unsigned short* __restrict__ Bq, const unsigned short* __restrict__ Bk,
    const unsigned short* __restrict__ Bv,
    unsigned short* __restrict__ Qc, unsigned short* __restrict__ KV) {
    __shared__ unsigned short As[64 * 72];
    __shared__ unsigned short Bs[64 * 72];
    int bx = blockIdx.x;
    int which = bx >> 8, bb = bx & 255;
    const void* A1; const unsigned short* Bt; const unsigned short* bias; int K;
    if (which == 0)      { A1 = peQv; Bt = WQt; bias = Bq; K = 1024; }
    else if (which == 1) { A1 = peKv; Bt = WKt; bias = Bk; K = 1024; }
    else                 { A1 = peQv; Bt = WVt; bias = Bv; K = 256; }
    int mb = bb & 63, nb = bb >> 6;
    int m0 = mb * 64, n0 = nb * 64;
    int t = threadIdx.x, w = t >> 6, lane = t & 63;
    int ln = lane & 15, q8 = (lane >> 4) * 8;
    int wm = (w >> 1) * 32, wn = (w & 1) * 32;
    int sr = t >> 3, sc = (t & 7) * 8;
    f32x4 acc[2][2];
#pragma unroll
    for (int i = 0; i < 2; i++)
#pragma unroll
        for (int j = 0; j < 2; j++) acc[i][j] = (f32x4){0.f, 0.f, 0.f, 0.f};
    for (int kb = 0; kb < K; kb += 64) {
#pragma unroll
        for (int half = 0; half < 2; half++) {
            int r = sr + half * 32;
            int c = kb + sc;
            if (ABF16) {
                const unsigned short* ap = (c < 256)
                    ? ((const unsigned short*)xv + (m0 + r) * 256 + c)
                    : ((const unsigned short*)A1 + (m0 + r) * 768 + (c - 256));
                *(uint4*)&As[r * 72 + sc] = *(const uint4*)ap;
            } else {
                const float* ap = (c < 256)
                    ? ((const float*)xv + (m0 + r) * 256 + c)
                    : ((const float*)A1 + (m0 + r) * 768 + (c - 256));
                float4 u0 = *(const float4*)ap;
                float4 u1 = *(const float4*)(ap + 4);
                union { unsigned u[4]; uint4 v; } pk;
                pk.u[0] = pk2(u0.x, u0.y); pk.u[1] = pk2(u0.z, u0.w);
                pk.u[2] = pk2(u1.x, u1.y); pk.u[3] = pk2(u1.z, u1.w);
                *(uint4*)&As[r * 72 + sc] = pk.v;
            }
            *(uint4*)&Bs[r * 72 + sc] = *(const uint4*)(Bt + (n0 + r) * K + c);
        }
        __syncthreads();
#pragma unroll
        for (int ks = 0; ks < 64; ks += 32) {
            bf16x8 a[2], b[2];
#pragma unroll
            for (int i = 0; i < 2; i++) {
                a[i] = *(const bf16x8*)&As[(wm + i * 16 + ln) * 72 + ks + q8];
                b[i] = *(const bf16x8*)&Bs[(wn + i * 16 + ln) * 72 + ks + q8];
            }
#pragma unroll
            for (int i = 0; i < 2; i++)
#pragma unroll
                for (int j = 0; j < 2; j++)
                    acc[i][j] = __builtin_amdgcn_mfma_f32_16x16x32_bf16(a[i], b[j], acc[i][j], 0, 0, 0);
        }
        __syncthreads();
    }
#pragma unroll
    for (int j = 0; j < 2; j++) {
        int ncol = n0 + wn + j * 16 + ln;
        float bv = b2f(bias[ncol]);
        int h2 = ncol >> 5, din = ncol & 31;
#pragma unroll
        for (int i = 0; i < 2; i++) {
            int rbase = m0 + wm + i * 16 + ((lane >> 4) * 4);
            if (which == 0) {
#pragma unroll
                for (int r = 0; r < 4; r++)
                    Qc[(rbase + r) * 256 + ncol] = f2b(acc[i][j][r] + bv);
            } else if (which == 1) {
#pragma unroll
                for (int r = 0; r < 4; r++) {
                    int key = rbase + r;
                    int T2 = key >> 6, k6 = key & 63;
                    int kt = ((k6 >> 2) & 1) + ((k6 >> 4) & 2);
                    int ln2 = ((k6 >> 3) & 3) * 4 + (k6 & 3);
                    int addr = (h2 * 64 + T2) * 4096 + kt * 512
                             + ((din >> 3) * 16 + ln2) * 8 + (din & 7);
                    KV[addr] = f2b(acc[i][j][r] + bv);
                }
            } else {
                int key = rbase;
                int T2 = key >> 6, k6 = key & 63;
                int chunk = 4 + ((din >> 4) << 1) + ((k6 >> 5) & 1);
                int lane2 = ((k6 >> 3) & 3) * 16 + (din & 15);
                int addr = (h2 * 64 + T2) * 4096 + chunk * 512 + lane2 * 8 + (k6 & 7);
                uint2 vv;
                vv.x = pk2(acc[i][j][0] + bv, acc[i][j][1] + bv);
                vv.y = pk2(acc[i][j][2] + bv, acc[i][j][3] + bv);
                *(uint2*)(KV + addr) = vv;
            }
        }
    }
}

// ---------- flash attention v7: v5 compute + 8 waves + conflict-free staging ----------
// v5's counters isolated three defects, each fixed here:
//  (1) 2 waves/SIMD -> now 8 waves/block (4 row-groups x 2 KEY-groups), 512-thr
//      blocks, 2 blocks/CU = 16 waves/CU; cheap 2-way LDS combine at the end.
//  (2) prefetch sunk by compiler (VGPR=28) -> only 8 regs in flight (na/nb),
//      pinned between sched_barrier(0)s: load || compute || ds_write order forced.
//  (3) 16-way ds_write bank conflicts (2.1M) -> lanes write l*16 within a 1KB
//      span (2-way = free); 1 barrier/tile (write targets non-read buffer).
// Keeps v5's verified compute body: lane-local output, mfma(ones,P) denominator.
__global__ __launch_bounds__(512, 2) void attn_kernel(
    const unsigned short* __restrict__ Qc,
    const unsigned short* __restrict__ KV,
    unsigned short* __restrict__ Xc) {
    __shared__ unsigned short Kt[2][2][4096];  // [dbuf][key-group][8KB tile]
    __shared__ float Osum[2][4][16][33];
    __shared__ float Dsum[2][4][16];
    int head = blockIdx.x & 7;
    int qb = blockIdx.x >> 3;
    int q0 = qb * 64;
    int tid = threadIdx.x, w = tid >> 6, lane = tid & 63;
    int ln = lane & 15, quad = lane >> 4, q8 = quad * 8;
    int wr = w & 3, kg = w >> 2;
    int qrow = q0 + wr * 16 + ln;
    bf16x8 qv = *(const bf16x8*)(Qc + qrow * 256 + head * 32 + q8);
    bf16x8 ones;
#pragma unroll
    for (int i = 0; i < 8; i++) ones[i] = (short)0x3F80;  // bf16 1.0
    const f32x4 z = {0.f, 0.f, 0.f, 0.f};
    f32x4 o0 = z, o1 = z, lacc = z;
    const unsigned short* panel = KV + head * 64 * 4096;
    // staging coordinates: thread stages 32B of the tile for key-group sh
    int sh = tid >> 8;                          // 0/1: which kg tile to stage
    int so0 = (wr * 2 + 0) * 512 + lane * 8;    // shorts offset in tile
    int so1 = (wr * 2 + 1) * 512 + lane * 8;    // (lane*16B within 1KB span)
    // prologue: stage tile {sh*32 + 0} into buffer 0
    {
        const unsigned short* gp = panel + (sh * 32) * 4096;
        uint4 a = *(const uint4*)(gp + so0);
        uint4 b = *(const uint4*)(gp + so1);
        *(uint4*)&Kt[0][sh][so0] = a;
        *(uint4*)&Kt[0][sh][so1] = b;
    }
    __syncthreads();
#pragma unroll 1
    for (int it = 0; it < 32; ++it) {
        int cur = it & 1;
        uint4 na, nb;
        if (it < 31) {
            const unsigned short* gp = panel + (sh * 32 + it + 1) * 4096;
            na = *(const uint4*)(gp + so0);
            nb = *(const uint4*)(gp + so1);
        }
        __builtin_amdgcn_sched_barrier(0);
        const unsigned short* kb = &Kt[cur][kg][0];
        bf16x8 k0 = *(const bf16x8*)(kb + lane * 8);
        bf16x8 k1 = *(const bf16x8*)(kb + 512 + lane * 8);
        bf16x8 k2 = *(const bf16x8*)(kb + 1024 + lane * 8);
        bf16x8 k3 = *(const bf16x8*)(kb + 1536 + lane * 8);
        bf16x8 v0 = *(const bf16x8*)(kb + 2048 + lane * 8);
        bf16x8 v1 = *(const bf16x8*)(kb + 2560 + lane * 8);
        bf16x8 v2 = *(const bf16x8*)(kb + 3072 + lane * 8);
        bf16x8 v3 = *(const bf16x8*)(kb + 3584 + lane * 8);
        f32x4 s0 = __builtin_amdgcn_mfma_f32_16x16x32_bf16(k0, qv, z, 0, 0, 0);
        f32x4 s1 = __builtin_amdgcn_mfma_f32_16x16x32_bf16(k1, qv, z, 0, 0, 0);
        f32x4 s2 = __builtin_amdgcn_mfma_f32_16x16x32_bf16(k2, qv, z, 0, 0, 0);
        f32x4 s3 = __builtin_amdgcn_mfma_f32_16x16x32_bf16(k3, qv, z, 0, 0, 0);
        float p0[4], p1[4], p2[4], p3[4];
#pragma unroll
        for (int r = 0; r < 4; r++) {
            p0[r] = __builtin_amdgcn_exp2f(s0[r]);
            p1[r] = __builtin_amdgcn_exp2f(s1[r]);
            p2[r] = __builtin_amdgcn_exp2f(s2[r]);
            p3[r] = __builtin_amdgcn_exp2f(s3[r]);
        }
        union { unsigned u[4]; bf16x8 v; } pa, pb;
        pa.u[0] = pk2(p0[0], p0[1]); pa.u[1] = pk2(p0[2], p0[3]);
        pa.u[2] = pk2(p1[0], p1[1]); pa.u[3] = pk2(p1[2], p1[3]);
        pb.u[0] = pk2(p2[0], p2[1]); pb.u[1] = pk2(p2[2], p2[3]);
        pb.u[2] = pk2(p3[0], p3[1]); pb.u[3] = pk2(p3[2], p3[3]);
        lacc = __builtin_amdgcn_mfma_f32_16x16x32_bf16(ones, pa.v, lacc, 0, 0, 0);
        lacc = __builtin_amdgcn_mfma_f32_16x16x32_bf16(ones, pb.v, lacc, 0, 0, 0);
        o0 = __builtin_amdgcn_mfma_f32_16x16x32_bf16(v0, pa.v, o0, 0, 0, 0);
        o0 = __builtin_amdgcn_mfma_f32_16x16x32_bf16(v1, pb.v, o0, 0, 0, 0);
        o1 = __builtin_amdgcn_mfma_f32_16x16x32_bf16(v2, pa.v, o1, 0, 0, 0);
        o1 = __builtin_amdgcn_mfma_f32_16x16x32_bf16(v3, pb.v, o1, 0, 0, 0);
        __builtin_amdgcn_sched_barrier(0);
        if (it < 31) {
            int nxt = cur ^ 1;
            *(uint4*)&Kt[nxt][sh][so0] = na;
            *(uint4*)&Kt[nxt][sh][so1] = nb;
        }
        __syncthreads();
    }
    // 2-way combine across key-groups
#pragma unroll
    for (int r = 0; r < 4; r++) {
        Osum[kg][wr][ln][quad * 4 + r] = o0[r];
        Osum[kg][wr][ln][16 + quad * 4 + r] = o1[r];
    }
    if (quad == 0) Dsum[kg][wr][ln] = lacc[0];
    __syncthreads();
    int qr = tid >> 3, d0 = (tid & 7) * 4;
    int rw = qr >> 4, rl = qr & 15;
    float den = Dsum[0][rw][rl] + Dsum[1][rw][rl];
    float inv = 1.f / den;
    float f0 = Osum[0][rw][rl][d0 + 0] + Osum[1][rw][rl][d0 + 0];
    float f1 = Osum[0][rw][rl][d0 + 1] + Osum[1][rw][rl][d0 + 1];
    float f2v = Osum[0][rw][rl][d0 + 2] + Osum[1][rw][rl][d0 + 2];
    float f3 = Osum[0][rw][rl][d0 + 3] + Osum[1][rw][rl][d0 + 3];
    uint2 outv;
    outv.x = pk2(f0 * inv, f1 * inv);
    outv.y = pk2(f2v * inv, f3 * inv);
    *(uint2*)(Xc + (q0 + qr) * 256 + head * 32 + d0) = outv;
}

// ---------- final GEMM: d_out f32 = Xc(bf16) @ lin_w^T + lin_b ----------
template <bool BBF16>
__global__ __launch_bounds__(256) void gemm_out(
    const unsigned short* __restrict__ A,
    const void* __restrict__ LWv,
    const float* __restrict__ Lb,
    float* __restrict__ C) {
    __shared__ unsigned short As[64 * 72];
    __shared__ unsigned short Bs[64 * 72];
    int mb = blockIdx.x & 63, nb = blockIdx.x >> 6;
    int m0 = mb * 64, n0 = nb * 64;
    int t = threadIdx.x, w = t >> 6, lane = t & 63;
    int ln = lane & 15, q8 = (lane >> 4) * 8;
    int wm = (w >> 1) * 32, wn = (w & 1) * 32;
    int sr = t >> 3, sc = (t & 7) * 8;
    f32x4 acc[2][2];
#pragma unroll
    for (int i = 0; i < 2; i++)
#pragma unroll
        for (int j = 0; j < 2; j++) acc[i][j] = (f32x4){0.f, 0.f, 0.f, 0.f};
    for (int kb = 0; kb < 256; kb += 64) {
#pragma unroll
        for (int half = 0; half < 2; half++) {
            int r = sr + half * 32;
            int c = kb + sc;
            *(uint4*)&As[r * 72 + sc] = *(const uint4*)(A + (m0 + r) * 256 + c);
            if (BBF16) {
                *(uint4*)&Bs[r * 72 + sc] =
                    *(const uint4*)((const unsigned short*)LWv + (n0 + r) * 256 + c);
            } else {
                const float* bp = (const float*)LWv + (n0 + r) * 256 + c;
                float4 u0 = *(const float4*)bp;
                float4 u1 = *(const float4*)(bp + 4);
                union { unsigned u[4]; uint4 v; } pk;
                pk.u[0] = pk2(u0.x, u0.y); pk.u[1] = pk2(u0.z, u0.w);
                pk.u[2] = pk2(u1.x, u1.y); pk.u[3] = pk2(u1.z, u1.w);
                *(uint4*)&Bs[r * 72 + sc] = pk.v;
            }
        }
        __syncthreads();
#pragma unroll
        for (int ks = 0; ks < 64; ks += 32) {
            bf16x8 a[2], b[2];
#pragma unroll
            for (int i = 0; i < 2; i++) {
                a[i] = *(const bf16x8*)&As[(wm + i * 16 + ln) * 72 + ks + q8];
                b[i] = *(const bf16x8*)&Bs[(wn + i * 16 + ln) * 72 + ks + q8];
            }
#pragma unroll
            for (int i = 0; i < 2; i++)
#pragma unroll
                for (int j = 0; j < 2; j++)
                    acc[i][j] = __builtin_amdgcn_mfma_f32_16x16x32_bf16(a[i], b[j], acc[i][j], 0, 0, 0);
        }
        __syncthreads();
    }
#pragma unroll
    for (int j = 0; j < 2; j++) {
        int ncol = n0 + wn + j * 16 + ln;
        float bv = Lb[ncol];
#pragma unroll
        for (int i = 0; i < 2; i++) {
            int rbase = m0 + wm + i * 16 + ((lane >> 4) * 4);
#pragma unroll
            for (int r = 0; r < 4; r++)
                C[(rbase + r) * 256 + ncol] = acc[i][j][r] + bv;
        }
    }
}

extern "C" void kernel_launch(void* const* d_in, const int* in_sizes, int n_in,
                              void* d_out, int out_size, void* d_ws, size_t ws_size,
                              hipStream_t stream) {
    const float* input_x = (const float*)d_in[0];
    const float* pe_Q    = (const float*)d_in[1];
    const float* pe_K    = (const float*)d_in[2];
    // d_in[3] = A (unused)
    const float* WQ = (const float*)d_in[4];
    const float* WK = (const float*)d_in[5];
    const float* WV = (const float*)d_in[6];
    const float* Qb = (const float*)d_in[7];
    const float* Kb = (const float*)d_in[8];
    const float* Vb = (const float*)d_in[9];
    const float* lw = (const float*)d_in[10];
    const float* lb = (const float*)d_in[11];
    float* outp = (float*)d_out;

    unsigned short* ws = (unsigned short*)d_ws;
    unsigned short* WQt = ws;                  // 262144
    unsigned short* WKt = WQt + 262144;        // 262144
    unsigned short* WVt = WKt + 262144;        // 65536
    unsigned short* LWt = WVt + 65536;         // 65536
    unsigned short* Bq  = LWt + 65536;         // 256 x3
    unsigned short* Bk  = Bq + 256;
    unsigned short* Bv  = Bk + 256;
    unsigned short* xb   = Bv + 256;           // 1048576
    unsigned short* peQb = xb + 1048576;       // 3145728
    unsigned short* peKb = peQb + 3145728;     // 3145728
    unsigned short* Qc   = peKb + 3145728;     // 1048576
    unsigned short* KVb  = Qc + 1048576;       // 2097152
    unsigned short* Xc   = KVb + 2097152;      // 1048576
    size_t need = (size_t)(Xc + 1048576 - ws) * 2;

    if (ws_size >= need) {
        prep_main<<<dim3(3905), dim3(256), 0, stream>>>(
            WQ, WK, WV, lw, Qb, Kb, Vb, input_x, pe_Q, pe_K,
            WQt, WKt, WVt, LWt, Bq, Bk, Bv, xb, peQb, peKb);
        proj_fused<true><<<dim3(768), dim3(256), 0, stream>>>(
            xb, peQb, peKb, WQt, WKt, WVt, Bq, Bk, Bv, Qc, KVb);
        attn_kernel<<<dim3(512), dim3(512), 0, stream>>>(Qc, KVb, Xc);
        gemm_out<true><<<dim3(256), dim3(256), 0, stream>>>(Xc, LWt, lb, outp);
    } else {
        // fallback (f32 staging), smaller footprint
        unsigned short* Qc2  = Bv + 256;
        unsigned short* KV2  = Qc2 + 1048576;
        unsigned short* Xc2  = KV2 + 2097152;
        prep_fb<<<dim3(289), dim3(256), 0, stream>>>(WQ, WK, WV, Qb, Kb, Vb,
                                                     WQt, WKt, WVt, Bq, Bk, Bv);
        proj_fused<false><<<dim3(768), dim3(256), 0, stream>>>(
            input_x, pe_Q, pe_K, WQt, WKt, WVt, Bq, Bk, Bv, Qc2, KV2);
        attn_kernel<<<dim3(512), dim3(512), 0, stream>>>(Qc2, KV2, Xc2);
        gemm_out<false><<<dim3(256), dim3(256), 0, stream>>>(Xc2, lw, lb, outp);
    }
}